// Round 1
// baseline (540.714 us; speedup 1.0000x reference)
//
#include <hip/hip_runtime.h>
#include <hip/hip_bf16.h>

#define N_NODES 20000
#define N_EDGES 320000
#define HD 512

typedef __attribute__((ext_vector_type(8))) short bf16x8;
typedef __attribute__((ext_vector_type(4))) float f32x4;

// ---------- bf16 helpers ----------
__device__ inline ushort f2bf(float f) {
    uint u = __float_as_uint(f);
    uint r = (u + 0x7fffu + ((u >> 16) & 1u)) >> 16;
    return (ushort)r;
}
__device__ inline uint pack2(float a, float b) {
    return (uint)f2bf(a) | ((uint)f2bf(b) << 16);
}
__device__ inline float bflo(uint u) { return __uint_as_float(u << 16); }
__device__ inline float bfhi(uint u) { return __uint_as_float(u & 0xffff0000u); }

__device__ __forceinline__ void async_load16(const void* g, void* l) {
    __builtin_amdgcn_global_load_lds(
        (const __attribute__((address_space(1))) uint*)g,
        (__attribute__((address_space(3))) uint*)l,
        16, 0, 0);
}

// ---------- gemm tile: 128x128, global_load_lds, XOR swizzle (proven) -------
__device__ __forceinline__ void gemm_tile(const ushort* __restrict__ A,
                                          const ushort* __restrict__ Bt,
                                          ushort* __restrict__ C,
                                          int tile, char* smem) {
    short* As = (short*)smem;
    short* Bs = (short*)(smem + 128 * 32 * 2);
    const int tid = threadIdx.x;
    const int lane = tid & 63;
    const int wave = tid >> 6;
    const int l15 = lane & 15;
    const int q = lane >> 4;
    const int wrow = wave >> 1, wcol = wave & 1;
    const int row0 = (tile >> 2) * 128;
    const int col0 = (tile & 3) * 128;

    const int srow = lane >> 2;
    const int kc   = (lane & 3) ^ ((lane >> 3) & 3);
    const int sl   = (l15 >> 1) & 3;

    f32x4 acc[4][4] = {};

    for (int k0 = 0; k0 < HD; k0 += 32) {
        #pragma unroll
        for (int l = 0; l < 2; ++l) {
            const int rbase = wave * 32 + l * 16;
            const ushort* ga = &A [(size_t)(row0 + rbase + srow) * HD + k0 + kc * 8];
            const ushort* gb = &Bt[(size_t)(col0 + rbase + srow) * HD + k0 + kc * 8];
            async_load16(ga, &As[rbase * 32]);
            async_load16(gb, &Bs[rbase * 32]);
        }
        __syncthreads();
        bf16x8 aF[4], bF[4];
        #pragma unroll
        for (int i = 0; i < 4; ++i)
            aF[i] = *(bf16x8*)&As[(wrow * 64 + i * 16 + l15) * 32 + (q ^ sl) * 8];
        #pragma unroll
        for (int j = 0; j < 4; ++j)
            bF[j] = *(bf16x8*)&Bs[(wcol * 64 + j * 16 + l15) * 32 + (q ^ sl) * 8];
        #pragma unroll
        for (int i = 0; i < 4; ++i)
            #pragma unroll
            for (int j = 0; j < 4; ++j)
                acc[i][j] = __builtin_amdgcn_mfma_f32_16x16x32_bf16(aF[i], bF[j], acc[i][j], 0, 0, 0);
        __syncthreads();
    }
    #pragma unroll
    for (int i = 0; i < 4; ++i) {
        #pragma unroll
        for (int r = 0; r < 4; ++r) {
            int gr = row0 + wrow * 64 + i * 16 + q * 4 + r;
            if (gr < N_NODES) {
                #pragma unroll
                for (int j = 0; j < 4; ++j) {
                    int gc = col0 + wcol * 64 + j * 16 + l15;
                    C[(size_t)gr * HD + gc] = f2bf(acc[i][j][r]);
                }
            }
        }
    }
}

// ---------- pool partial (proven) ----------
__device__ __forceinline__ void pool_part(const ushort* __restrict__ h,
                                          float* __restrict__ pmax,
                                          float* __restrict__ psum,
                                          int pb, char* smem) {
    float* lmx = (float*)smem;           // 2048 floats
    float* lsm = lmx + 2048;             // 2048 floats
    const int tid = threadIdx.x;
    const int wave = tid >> 6, lane = tid & 63;
    const uint4* h4 = (const uint4*)h;
    float m[8] = {}, sm[8] = {};
    for (int r = pb * 4 + wave; r < N_NODES; r += 1024) {
        uint4 v = h4[(size_t)r * 64 + lane];
        m[0] = fmaxf(m[0], bflo(v.x)); sm[0] += bflo(v.x);
        m[1] = fmaxf(m[1], bfhi(v.x)); sm[1] += bfhi(v.x);
        m[2] = fmaxf(m[2], bflo(v.y)); sm[2] += bflo(v.y);
        m[3] = fmaxf(m[3], bfhi(v.y)); sm[3] += bfhi(v.y);
        m[4] = fmaxf(m[4], bflo(v.z)); sm[4] += bflo(v.z);
        m[5] = fmaxf(m[5], bfhi(v.z)); sm[5] += bfhi(v.z);
        m[6] = fmaxf(m[6], bflo(v.w)); sm[6] += bflo(v.w);
        m[7] = fmaxf(m[7], bfhi(v.w)); sm[7] += bfhi(v.w);
    }
    #pragma unroll
    for (int i = 0; i < 8; ++i) {
        lmx[wave * 512 + lane * 8 + i] = m[i];
        lsm[wave * 512 + lane * 8 + i] = sm[i];
    }
    __syncthreads();
    #pragma unroll
    for (int cc = 0; cc < 2; ++cc) {
        int ch = tid * 2 + cc;
        float mx = fmaxf(fmaxf(lmx[ch], lmx[512 + ch]),
                         fmaxf(lmx[1024 + ch], lmx[1536 + ch]));
        float sv = (lsm[ch] + lsm[512 + ch]) + (lsm[1024 + ch] + lsm[1536 + ch]);
        atomicMax((int*)&pmax[ch], __float_as_int(mx));   // values >= 0
        atomicAdd(&psum[ch], sv);
    }
}

// ---------- prep: cvt x | wt transpose | zero deg/pmax/psum ----------
#define NB_CVT 5000
#define NB_WT  192
#define NB_ZD  79
__global__ __launch_bounds__(256) void prep_k(const float* __restrict__ x,
                                              ushort* __restrict__ xb,
                                              const float* __restrict__ W1,
                                              const float* __restrict__ W2,
                                              const float* __restrict__ W3,
                                              ushort* __restrict__ T1,
                                              ushort* __restrict__ T2,
                                              ushort* __restrict__ T3,
                                              int* __restrict__ deg,
                                              float* __restrict__ pmax,
                                              float* __restrict__ psum) {
    __shared__ float t[64][65];
    const int b = blockIdx.x;
    const int tid = threadIdx.x;
    if (b < NB_CVT) {
        int c = b * 256 + tid;
        const float4* p = (const float4*)x + (size_t)c * 2;
        float4 a = p[0], q = p[1];
        uint4 o;
        o.x = pack2(a.x, a.y); o.y = pack2(a.z, a.w);
        o.z = pack2(q.x, q.y); o.w = pack2(q.z, q.w);
        ((uint4*)xb)[c] = o;
    } else if (b < NB_CVT + NB_WT) {
        int idx = b - NB_CVT;
        int layer = idx >> 6, rem = idx & 63;
        const float* W = (layer == 0) ? W1 : (layer == 1) ? W2 : W3;
        ushort* T      = (layer == 0) ? T1 : (layer == 1) ? T2 : T3;
        int kb = (rem >> 3) * 64, nb = (rem & 7) * 64;
        int c = tid & 63, r4 = tid >> 6;
        #pragma unroll
        for (int l = 0; l < 16; ++l) {
            int r = l * 4 + r4;
            t[r][c] = W[(size_t)(kb + r) * HD + nb + c];
        }
        __syncthreads();
        #pragma unroll
        for (int l = 0; l < 16; ++l) {
            int r = l * 4 + r4;
            T[(size_t)(nb + r) * HD + kb + c] = f2bf(t[c][r]);
        }
    } else if (b < NB_CVT + NB_WT + NB_ZD) {
        int i = (b - NB_CVT - NB_WT) * 256 + tid;
        if (i < N_NODES) deg[i] = 0;
    } else if (b < NB_CVT + NB_WT + NB_ZD + 6) {
        int i = (b - NB_CVT - NB_WT - NB_ZD) * 256 + tid;
        pmax[i] = 0.f;
    } else {
        int i = (b - NB_CVT - NB_WT - NB_ZD - 6) * 256 + tid;
        psum[i] = 0.f;
    }
}

// ---------- fused1: gemm layer1 (0..627) || hist (628..1877) ----------
__global__ __launch_bounds__(256) void fused1_k(const ushort* __restrict__ xb,
                                                const ushort* __restrict__ wt1,
                                                ushort* __restrict__ s,
                                                const int* __restrict__ rows,
                                                int* __restrict__ deg) {
    __shared__ __align__(16) char smem[16384];
    const int b = blockIdx.x;
    if (b < 628) {
        gemm_tile(xb, wt1, s, b, smem);
    } else {
        int e = (b - 628) * 256 + threadIdx.x;   // 1250*256 == N_EDGES exactly
        atomicAdd(&deg[rows[e]], 1);
    }
}

// ---------- scan: one workgroup, 16 waves, shuffle (proven ~4 µs) ----------
__global__ __launch_bounds__(1024) void scan_k(const int* __restrict__ deg,
                                               int* __restrict__ rowstart,
                                               int* __restrict__ cursor) {
    __shared__ int wsum[16];
    const int tid = threadIdx.x;
    const int lane = tid & 63, wv = tid >> 6;
    int carry = 0;
    for (int base = 0; base < N_NODES; base += 1024) {
        int i = base + tid;
        int v = (i < N_NODES) ? deg[i] : 0;
        int incl = v;
        #pragma unroll
        for (int off = 1; off < 64; off <<= 1) {
            int t = __shfl_up(incl, off, 64);
            if (lane >= off) incl += t;
        }
        if (lane == 63) wsum[wv] = incl;
        __syncthreads();
        int woff = 0, tot = 0;
        #pragma unroll
        for (int w = 0; w < 16; ++w) {
            int sv = wsum[w];
            if (w < wv) woff += sv;
            tot += sv;
        }
        if (i < N_NODES) {
            int ex = carry + woff + incl - v;
            rowstart[i] = ex;
            cursor[i]   = ex;
        }
        carry += tot;
        __syncthreads();
    }
    if (tid == 0) rowstart[N_NODES] = carry;
}

// ---------- fill CSR ----------
__global__ void fill_k(const int* __restrict__ rows, const int* __restrict__ cols,
                       const float* __restrict__ vals, int* __restrict__ cursor,
                       int* __restrict__ csr_col, float* __restrict__ csr_val) {
    int e = blockIdx.x * blockDim.x + threadIdx.x;
    if (e < N_EDGES) {
        int p = atomicAdd(&cursor[rows[e]], 1);
        csr_col[p] = cols[e];
        csr_val[p] = vals[e];
    }
}

// ---------- aggregate: channel-sliced, XCD-pinned, L2-resident gather -------
// Block = 4 rows x one 64-channel slice. slice = blockIdx.x % 8: with default
// round-robin WG->XCD dispatch, each XCD's gathers touch only a
// 20000 x 128 B = 2.56 MB slice of s -> fits its 4 MB L2 (vs 20.5 MB before).
// Lanes 0..31 gather edge j's 128 B slice, lanes 32..63 gather edge j+1;
// shfl_xor(32) merges halves at the end. Metadata + output are non-temporal
// so the streamed data doesn't evict the hot gather slice.
__global__ __launch_bounds__(256) void agg_k(const ushort* __restrict__ s,
                                             const int* __restrict__ rowstart,
                                             const int* __restrict__ csr_col,
                                             const float* __restrict__ csr_val,
                                             const float* __restrict__ bias,
                                             ushort* __restrict__ hout) {
    const int slice = blockIdx.x & 7;          // XCD-pinned channel slice
    const int rg    = blockIdx.x >> 3;
    const int wave = threadIdx.x >> 6, lane = threadIdx.x & 63;
    const int half = lane >> 5, cpos = lane & 31;
    const int r = rg * 4 + wave;
    const uint* sb = (const uint*)s + slice * 32 + cpos;   // + col*256 per edge
    float a0 = 0.f, a1 = 0.f;
    const int end = rowstart[r + 1];
    int j = rowstart[r] + half;                // this half's edges: j, j+2, ...
    for (; j + 6 < end; j += 8) {              // 4 edges/half, 8/wave in flight
        int   c0 = __builtin_nontemporal_load(&csr_col[j]);
        int   c1 = __builtin_nontemporal_load(&csr_col[j + 2]);
        int   c2 = __builtin_nontemporal_load(&csr_col[j + 4]);
        int   c3 = __builtin_nontemporal_load(&csr_col[j + 6]);
        float w0 = __builtin_nontemporal_load(&csr_val[j]);
        float w1 = __builtin_nontemporal_load(&csr_val[j + 2]);
        float w2 = __builtin_nontemporal_load(&csr_val[j + 4]);
        float w3 = __builtin_nontemporal_load(&csr_val[j + 6]);
        uint v0 = sb[(size_t)c0 << 8];
        uint v1 = sb[(size_t)c1 << 8];
        uint v2 = sb[(size_t)c2 << 8];
        uint v3 = sb[(size_t)c3 << 8];
        a0 += w0 * bflo(v0); a1 += w0 * bfhi(v0);
        a0 += w1 * bflo(v1); a1 += w1 * bfhi(v1);
        a0 += w2 * bflo(v2); a1 += w2 * bfhi(v2);
        a0 += w3 * bflo(v3); a1 += w3 * bfhi(v3);
    }
    for (; j < end; j += 2) {
        int   c = csr_col[j];
        float w = csr_val[j];
        uint  v = sb[(size_t)c << 8];
        a0 += w * bflo(v); a1 += w * bfhi(v);
    }
    a0 += __shfl_xor(a0, 32, 64);              // merge the two edge-halves
    a1 += __shfl_xor(a1, 32, 64);
    if (half == 0) {
        float2 bb = ((const float2*)bias)[slice * 32 + cpos];
        uint o = pack2(fmaxf(a0 + bb.x, 0.f), fmaxf(a1 + bb.y, 0.f));
        __builtin_nontemporal_store(o, (uint*)hout + (size_t)r * 256 + slice * 32 + cpos);
    }
}

// ---------- fused gemm || pool (both read-only on h; proven) ----------
__global__ __launch_bounds__(256) void fusedgp_k(const ushort* __restrict__ h,
                                                 const ushort* __restrict__ wt,
                                                 ushort* __restrict__ s,
                                                 float* __restrict__ pmax,
                                                 float* __restrict__ psum) {
    __shared__ __align__(16) char smem[16384];
    const int b = blockIdx.x;
    if (b < 628) gemm_tile(h, wt, s, b, smem);
    else         pool_part(h, pmax, psum, b - 628, smem);
}

// ---------- standalone pool (layer 3) ----------
__global__ __launch_bounds__(256) void pool_k(const ushort* __restrict__ h,
                                              float* __restrict__ pmax,
                                              float* __restrict__ psum) {
    __shared__ __align__(16) char smem[16384];
    pool_part(h, pmax, psum, blockIdx.x, smem);
}

// ---------- head MLP + log_softmax (1024 threads, split-k; proven) ----------
__global__ __launch_bounds__(1024) void mlp_k(const float* __restrict__ pool_max,
                                              const float* __restrict__ pool_sum,
                                              const float* __restrict__ l1W,
                                              const float* __restrict__ l1b,
                                              const float* __restrict__ l2W,
                                              const float* __restrict__ l2b,
                                              const float* __restrict__ l3W,
                                              const float* __restrict__ l3b,
                                              float* __restrict__ out) {
    __shared__ float g[1024];
    __shared__ float part[1024];
    __shared__ float a1[128];
    __shared__ float a2[64];
    __shared__ float a3[10];
    const int tid = threadIdx.x;
    if (tid < 512) {
        g[tid]       = pool_max[tid] + pool_max[512 + tid] + pool_max[1024 + tid];
        g[512 + tid] = (pool_sum[tid] + pool_sum[512 + tid] + pool_sum[1024 + tid]) *
                       (1.0f / N_NODES);
    }
    __syncthreads();
    {
        int ch = tid & 127, sl = tid >> 7;
        float acc = (sl == 0) ? l1b[ch] : 0.f;
        int k0 = sl * 128;
        #pragma unroll 4
        for (int k = k0; k < k0 + 128; ++k) acc += g[k] * l1W[k * 128 + ch];
        part[tid] = acc;
    }
    __syncthreads();
    if (tid < 128) {
        float a = part[tid];
        #pragma unroll
        for (int ss = 1; ss < 8; ++ss) a += part[tid + ss * 128];
        a1[tid] = fmaxf(a, 0.f);
    }
    __syncthreads();
    if (tid < 512) {
        int ch = tid & 63, sl = tid >> 6;
        float acc = (sl == 0) ? l2b[ch] : 0.f;
        int k0 = sl * 16;
        #pragma unroll
        for (int k = k0; k < k0 + 16; ++k) acc += a1[k] * l2W[k * 64 + ch];
        part[tid] = acc;
    }
    __syncthreads();
    if (tid < 64) {
        float a = part[tid];
        #pragma unroll
        for (int ss = 1; ss < 8; ++ss) a += part[tid + ss * 64];
        a2[tid] = fmaxf(a, 0.f);
    }
    __syncthreads();
    if (tid < 10) {
        float acc = l3b[tid];
        for (int k = 0; k < 64; ++k) acc += a2[k] * l3W[k * 10 + tid];
        a3[tid] = acc;
    }
    __syncthreads();
    if (tid == 0) {
        float m = a3[0];
        for (int j = 1; j < 10; ++j) m = fmaxf(m, a3[j]);
        float ssum = 0.f;
        for (int j = 0; j < 10; ++j) ssum += expf(a3[j] - m);
        float lse = m + logf(ssum);
        for (int j = 0; j < 10; ++j) out[j] = a3[j] - lse;
    }
}

extern "C" void kernel_launch(void* const* d_in, const int* in_sizes, int n_in,
                              void* d_out, int out_size, void* d_ws, size_t ws_size,
                              hipStream_t stream) {
    const float* x    = (const float*)d_in[0];
    const int*   rows = (const int*)  d_in[1];
    const int*   cols = (const int*)  d_in[2];
    const float* vals = (const float*)d_in[3];
    const float* W1   = (const float*)d_in[4];
    const float* b1   = (const float*)d_in[5];
    const float* W2   = (const float*)d_in[6];
    const float* b2   = (const float*)d_in[7];
    const float* W3   = (const float*)d_in[8];
    const float* b3   = (const float*)d_in[9];
    const float* l1W  = (const float*)d_in[10];
    const float* l1b  = (const float*)d_in[11];
    const float* l2W  = (const float*)d_in[12];
    const float* l2b  = (const float*)d_in[13];
    const float* l3W  = (const float*)d_in[14];
    const float* l3b  = (const float*)d_in[15];
    float* out = (float*)d_out;

    char* ws = (char*)d_ws;
    size_t off = 0;
    auto alloc = [&](size_t bytes) {
        void* p = ws + off;
        off += (bytes + 255) & ~(size_t)255;
        return p;
    };
    ushort* xb       = (ushort*)alloc((size_t)N_NODES * HD * 2);
    ushort* s        = (ushort*)alloc((size_t)N_NODES * HD * 2);
    ushort* hb       = (ushort*)alloc((size_t)N_NODES * HD * 2);
    ushort* wt1      = (ushort*)alloc((size_t)HD * HD * 2);
    ushort* wt2      = (ushort*)alloc((size_t)HD * HD * 2);
    ushort* wt3      = (ushort*)alloc((size_t)HD * HD * 2);
    int*    deg      = (int*)   alloc((size_t)N_NODES * 4);
    float*  pmax     = (float*) alloc((size_t)3 * 512 * 4);
    float*  psum     = (float*) alloc((size_t)3 * 512 * 4);
    int*    rowstart = (int*)   alloc((size_t)(N_NODES + 1) * 4);
    int*    cursor   = (int*)   alloc((size_t)N_NODES * 4);
    int*    csr_col  = (int*)   alloc((size_t)N_EDGES * 4);
    float*  csr_val  = (float*) alloc((size_t)N_EDGES * 4);
    (void)ws_size; (void)in_sizes; (void)n_in; (void)out_size;

    // 1: prep (cvt + wt + zero deg/pmax/psum)
    prep_k<<<NB_CVT + NB_WT + NB_ZD + 12, 256, 0, stream>>>(
        x, xb, W1, W2, W3, wt1, wt2, wt3, deg, pmax, psum);
    // 2: gemm1 || hist
    fused1_k<<<628 + 1250, 256, 0, stream>>>(xb, wt1, s, rows, deg);
    // 3: scan
    scan_k<<<1, 1024, 0, stream>>>(deg, rowstart, cursor);
    // 4: fill CSR
    fill_k<<<(N_EDGES + 255) / 256, 256, 0, stream>>>(rows, cols, vals, cursor,
                                                      csr_col, csr_val);
    const int AB = (N_NODES / 4) * 8;   // 5000 row-groups x 8 channel slices
    // 5: agg1
    agg_k<<<AB, 256, 0, stream>>>(s, rowstart, csr_col, csr_val, b1, hb);
    // 6: gemm2 || pool1
    fusedgp_k<<<628 + 256, 256, 0, stream>>>(hb, wt2, s, pmax, psum);
    // 7: agg2
    agg_k<<<AB, 256, 0, stream>>>(s, rowstart, csr_col, csr_val, b2, hb);
    // 8: gemm3 || pool2
    fusedgp_k<<<628 + 256, 256, 0, stream>>>(hb, wt3, s, pmax + 512, psum + 512);
    // 9: agg3
    agg_k<<<AB, 256, 0, stream>>>(s, rowstart, csr_col, csr_val, b3, hb);
    // 10: pool3
    pool_k<<<256, 256, 0, stream>>>(hb, pmax + 1024, psum + 1024);
    // 11: mlp head
    mlp_k<<<1, 1024, 0, stream>>>(pmax, psum, l1W, l1b, l2W, l2b, l3W, l3b, out);
}

// Round 2
// 439.822 us; speedup vs baseline: 1.2294x; 1.2294x over previous
//
#include <hip/hip_runtime.h>
#include <hip/hip_bf16.h>

#define N_NODES 20000
#define N_EDGES 320000
#define HD 512

typedef __attribute__((ext_vector_type(8))) short bf16x8;
typedef __attribute__((ext_vector_type(4))) float f32x4;

// ---------- bf16 helpers ----------
__device__ inline ushort f2bf(float f) {
    uint u = __float_as_uint(f);
    uint r = (u + 0x7fffu + ((u >> 16) & 1u)) >> 16;
    return (ushort)r;
}
__device__ inline uint pack2(float a, float b) {
    return (uint)f2bf(a) | ((uint)f2bf(b) << 16);
}
__device__ inline float bflo(uint u) { return __uint_as_float(u << 16); }
__device__ inline float bfhi(uint u) { return __uint_as_float(u & 0xffff0000u); }

__device__ __forceinline__ void async_load16(const void* g, void* l) {
    __builtin_amdgcn_global_load_lds(
        (const __attribute__((address_space(1))) uint*)g,
        (__attribute__((address_space(3))) uint*)l,
        16, 0, 0);
}

// ---------- gemm tile: 128x128, global_load_lds, XOR swizzle (proven) -------
__device__ __forceinline__ void gemm_tile(const ushort* __restrict__ A,
                                          const ushort* __restrict__ Bt,
                                          ushort* __restrict__ C,
                                          int tile, char* smem) {
    short* As = (short*)smem;
    short* Bs = (short*)(smem + 128 * 32 * 2);
    const int tid = threadIdx.x;
    const int lane = tid & 63;
    const int wave = tid >> 6;
    const int l15 = lane & 15;
    const int q = lane >> 4;
    const int wrow = wave >> 1, wcol = wave & 1;
    const int row0 = (tile >> 2) * 128;
    const int col0 = (tile & 3) * 128;

    const int srow = lane >> 2;
    const int kc   = (lane & 3) ^ ((lane >> 3) & 3);
    const int sl   = (l15 >> 1) & 3;

    f32x4 acc[4][4] = {};

    for (int k0 = 0; k0 < HD; k0 += 32) {
        #pragma unroll
        for (int l = 0; l < 2; ++l) {
            const int rbase = wave * 32 + l * 16;
            const ushort* ga = &A [(size_t)(row0 + rbase + srow) * HD + k0 + kc * 8];
            const ushort* gb = &Bt[(size_t)(col0 + rbase + srow) * HD + k0 + kc * 8];
            async_load16(ga, &As[rbase * 32]);
            async_load16(gb, &Bs[rbase * 32]);
        }
        __syncthreads();
        bf16x8 aF[4], bF[4];
        #pragma unroll
        for (int i = 0; i < 4; ++i)
            aF[i] = *(bf16x8*)&As[(wrow * 64 + i * 16 + l15) * 32 + (q ^ sl) * 8];
        #pragma unroll
        for (int j = 0; j < 4; ++j)
            bF[j] = *(bf16x8*)&Bs[(wcol * 64 + j * 16 + l15) * 32 + (q ^ sl) * 8];
        #pragma unroll
        for (int i = 0; i < 4; ++i)
            #pragma unroll
            for (int j = 0; j < 4; ++j)
                acc[i][j] = __builtin_amdgcn_mfma_f32_16x16x32_bf16(aF[i], bF[j], acc[i][j], 0, 0, 0);
        __syncthreads();
    }
    #pragma unroll
    for (int i = 0; i < 4; ++i) {
        #pragma unroll
        for (int r = 0; r < 4; ++r) {
            int gr = row0 + wrow * 64 + i * 16 + q * 4 + r;
            if (gr < N_NODES) {
                #pragma unroll
                for (int j = 0; j < 4; ++j) {
                    int gc = col0 + wcol * 64 + j * 16 + l15;
                    C[(size_t)gr * HD + gc] = f2bf(acc[i][j][r]);
                }
            }
        }
    }
}

// ---------- pool partial (proven) ----------
__device__ __forceinline__ void pool_part(const ushort* __restrict__ h,
                                          float* __restrict__ pmax,
                                          float* __restrict__ psum,
                                          int pb, char* smem) {
    float* lmx = (float*)smem;           // 2048 floats
    float* lsm = lmx + 2048;             // 2048 floats
    const int tid = threadIdx.x;
    const int wave = tid >> 6, lane = tid & 63;
    const uint4* h4 = (const uint4*)h;
    float m[8] = {}, sm[8] = {};
    for (int r = pb * 4 + wave; r < N_NODES; r += 1024) {
        uint4 v = h4[(size_t)r * 64 + lane];
        m[0] = fmaxf(m[0], bflo(v.x)); sm[0] += bflo(v.x);
        m[1] = fmaxf(m[1], bfhi(v.x)); sm[1] += bfhi(v.x);
        m[2] = fmaxf(m[2], bflo(v.y)); sm[2] += bflo(v.y);
        m[3] = fmaxf(m[3], bfhi(v.y)); sm[3] += bfhi(v.y);
        m[4] = fmaxf(m[4], bflo(v.z)); sm[4] += bflo(v.z);
        m[5] = fmaxf(m[5], bfhi(v.z)); sm[5] += bfhi(v.z);
        m[6] = fmaxf(m[6], bflo(v.w)); sm[6] += bflo(v.w);
        m[7] = fmaxf(m[7], bfhi(v.w)); sm[7] += bfhi(v.w);
    }
    #pragma unroll
    for (int i = 0; i < 8; ++i) {
        lmx[wave * 512 + lane * 8 + i] = m[i];
        lsm[wave * 512 + lane * 8 + i] = sm[i];
    }
    __syncthreads();
    #pragma unroll
    for (int cc = 0; cc < 2; ++cc) {
        int ch = tid * 2 + cc;
        float mx = fmaxf(fmaxf(lmx[ch], lmx[512 + ch]),
                         fmaxf(lmx[1024 + ch], lmx[1536 + ch]));
        float sv = (lsm[ch] + lsm[512 + ch]) + (lsm[1024 + ch] + lsm[1536 + ch]);
        atomicMax((int*)&pmax[ch], __float_as_int(mx));   // values >= 0
        atomicAdd(&psum[ch], sv);
    }
}

// ---------- prep: cvt x | wt transpose | zero deg/pmax/psum ----------
#define NB_CVT 5000
#define NB_WT  192
#define NB_ZD  79
__global__ __launch_bounds__(256) void prep_k(const float* __restrict__ x,
                                              ushort* __restrict__ xb,
                                              const float* __restrict__ W1,
                                              const float* __restrict__ W2,
                                              const float* __restrict__ W3,
                                              ushort* __restrict__ T1,
                                              ushort* __restrict__ T2,
                                              ushort* __restrict__ T3,
                                              int* __restrict__ deg,
                                              float* __restrict__ pmax,
                                              float* __restrict__ psum) {
    __shared__ float t[64][65];
    const int b = blockIdx.x;
    const int tid = threadIdx.x;
    if (b < NB_CVT) {
        int c = b * 256 + tid;
        const float4* p = (const float4*)x + (size_t)c * 2;
        float4 a = p[0], q = p[1];
        uint4 o;
        o.x = pack2(a.x, a.y); o.y = pack2(a.z, a.w);
        o.z = pack2(q.x, q.y); o.w = pack2(q.z, q.w);
        ((uint4*)xb)[c] = o;
    } else if (b < NB_CVT + NB_WT) {
        int idx = b - NB_CVT;
        int layer = idx >> 6, rem = idx & 63;
        const float* W = (layer == 0) ? W1 : (layer == 1) ? W2 : W3;
        ushort* T      = (layer == 0) ? T1 : (layer == 1) ? T2 : T3;
        int kb = (rem >> 3) * 64, nb = (rem & 7) * 64;
        int c = tid & 63, r4 = tid >> 6;
        #pragma unroll
        for (int l = 0; l < 16; ++l) {
            int r = l * 4 + r4;
            t[r][c] = W[(size_t)(kb + r) * HD + nb + c];
        }
        __syncthreads();
        #pragma unroll
        for (int l = 0; l < 16; ++l) {
            int r = l * 4 + r4;
            T[(size_t)(nb + r) * HD + kb + c] = f2bf(t[c][r]);
        }
    } else if (b < NB_CVT + NB_WT + NB_ZD) {
        int i = (b - NB_CVT - NB_WT) * 256 + tid;
        if (i < N_NODES) deg[i] = 0;
    } else if (b < NB_CVT + NB_WT + NB_ZD + 6) {
        int i = (b - NB_CVT - NB_WT - NB_ZD) * 256 + tid;
        pmax[i] = 0.f;
    } else {
        int i = (b - NB_CVT - NB_WT - NB_ZD - 6) * 256 + tid;
        psum[i] = 0.f;
    }
}

// ---------- fused1: gemm layer1 (0..627) || hist (628..1877) ----------
__global__ __launch_bounds__(256) void fused1_k(const ushort* __restrict__ xb,
                                                const ushort* __restrict__ wt1,
                                                ushort* __restrict__ s,
                                                const int* __restrict__ rows,
                                                int* __restrict__ deg) {
    __shared__ __align__(16) char smem[16384];
    const int b = blockIdx.x;
    if (b < 628) {
        gemm_tile(xb, wt1, s, b, smem);
    } else {
        int e = (b - 628) * 256 + threadIdx.x;   // 1250*256 == N_EDGES exactly
        atomicAdd(&deg[rows[e]], 1);
    }
}

// ---------- scan: one workgroup, 16 waves, shuffle (proven ~4 µs) ----------
__global__ __launch_bounds__(1024) void scan_k(const int* __restrict__ deg,
                                               int* __restrict__ rowstart,
                                               int* __restrict__ cursor) {
    __shared__ int wsum[16];
    const int tid = threadIdx.x;
    const int lane = tid & 63, wv = tid >> 6;
    int carry = 0;
    for (int base = 0; base < N_NODES; base += 1024) {
        int i = base + tid;
        int v = (i < N_NODES) ? deg[i] : 0;
        int incl = v;
        #pragma unroll
        for (int off = 1; off < 64; off <<= 1) {
            int t = __shfl_up(incl, off, 64);
            if (lane >= off) incl += t;
        }
        if (lane == 63) wsum[wv] = incl;
        __syncthreads();
        int woff = 0, tot = 0;
        #pragma unroll
        for (int w = 0; w < 16; ++w) {
            int sv = wsum[w];
            if (w < wv) woff += sv;
            tot += sv;
        }
        if (i < N_NODES) {
            int ex = carry + woff + incl - v;
            rowstart[i] = ex;
            cursor[i]   = ex;
        }
        carry += tot;
        __syncthreads();
    }
    if (tid == 0) rowstart[N_NODES] = carry;
}

// ---------- fill CSR (col+val packed into int2 -> one 8B load in agg) ------
__global__ void fill_k(const int* __restrict__ rows, const int* __restrict__ cols,
                       const float* __restrict__ vals, int* __restrict__ cursor,
                       int2* __restrict__ csr_cv) {
    int e = blockIdx.x * blockDim.x + threadIdx.x;
    if (e < N_EDGES) {
        int p = atomicAdd(&cursor[rows[e]], 1);
        csr_cv[p] = make_int2(cols[e], __float_as_int(vals[e]));
    }
}

// ---------- aggregate: channel-sliced + XCD-pinned + 8-edges-per-instr ------
// Block = 4 rows x one 64-channel slice. slice = blockIdx.x % 8 pins each
// slice to one XCD (round-robin WG dispatch): gather working set is
// 20000 x 128 B = 2.56 MB -> L2-resident (proven: FETCH 134->21 MB in r1).
// r1 regression fixed: lane = 8*edge_group + chunk, so one uint4 (16 B/lane)
// wave-instruction gathers EIGHT edges' 128 B slices at once (1 KB/instr,
// 4x fewer VMEM ops than r1). Metadata is one temporal 8B int2 load per
// edge-group (L3-cached across the 8 slice re-reads, vs r1's nontemporal
// HBM re-fetch). Cross-group reduce = 3 butterfly shfl_xor.
__device__ inline void fma8(float* acc, uint4 v, float w) {
    acc[0] += w * bflo(v.x); acc[1] += w * bfhi(v.x);
    acc[2] += w * bflo(v.y); acc[3] += w * bfhi(v.y);
    acc[4] += w * bflo(v.z); acc[5] += w * bfhi(v.z);
    acc[6] += w * bflo(v.w); acc[7] += w * bfhi(v.w);
}

__global__ __launch_bounds__(256) void agg_k(const ushort* __restrict__ s,
                                             const int* __restrict__ rowstart,
                                             const int2* __restrict__ csr_cv,
                                             const float* __restrict__ bias,
                                             ushort* __restrict__ hout) {
    const int slice = blockIdx.x & 7;          // XCD-pinned channel slice
    const int rg    = blockIdx.x >> 3;
    const int wave = threadIdx.x >> 6, lane = threadIdx.x & 63;
    const int g = lane >> 3, sub = lane & 7;   // edge-group, 16B channel chunk
    const int r = rg * 4 + wave;
    const uint4* s4 = (const uint4*)s;
    const size_t sbase = (size_t)slice * 8 + sub;
    float acc[8] = {};
    const int beg = rowstart[r], end = rowstart[r + 1];
    int j = beg;
    for (; j + 16 <= end; j += 16) {           // 16 edges, 2 gathers in flight
        int2 cv0 = csr_cv[j + g];
        int2 cv1 = csr_cv[j + 8 + g];
        uint4 v0 = s4[(size_t)cv0.x * 64 + sbase];
        uint4 v1 = s4[(size_t)cv1.x * 64 + sbase];
        fma8(acc, v0, __int_as_float(cv0.y));
        fma8(acc, v1, __int_as_float(cv1.y));
    }
    for (; j < end; j += 8) {                  // masked tail, 8 edges at a time
        bool act = (j + g) < end;
        int2 cv = act ? csr_cv[j + g] : make_int2(0, 0);
        uint4 v = s4[(size_t)cv.x * 64 + sbase];
        fma8(acc, v, act ? __int_as_float(cv.y) : 0.f);
    }
    #pragma unroll
    for (int off = 8; off <= 32; off <<= 1)    // reduce across 8 edge-groups
        #pragma unroll
        for (int i = 0; i < 8; ++i)
            acc[i] += __shfl_xor(acc[i], off, 64);
    if (g == 0) {                              // lanes 0..7 own chunk `sub`
        float4 b0 = ((const float4*)bias)[slice * 16 + sub * 2];
        float4 b1 = ((const float4*)bias)[slice * 16 + sub * 2 + 1];
        uint4 ov;
        ov.x = pack2(fmaxf(acc[0] + b0.x, 0.f), fmaxf(acc[1] + b0.y, 0.f));
        ov.y = pack2(fmaxf(acc[2] + b0.z, 0.f), fmaxf(acc[3] + b0.w, 0.f));
        ov.z = pack2(fmaxf(acc[4] + b1.x, 0.f), fmaxf(acc[5] + b1.y, 0.f));
        ov.w = pack2(fmaxf(acc[6] + b1.z, 0.f), fmaxf(acc[7] + b1.w, 0.f));
        ((uint4*)hout)[(size_t)r * 64 + slice * 8 + sub] = ov;
    }
}

// ---------- fused gemm || pool (both read-only on h; proven) ----------
__global__ __launch_bounds__(256) void fusedgp_k(const ushort* __restrict__ h,
                                                 const ushort* __restrict__ wt,
                                                 ushort* __restrict__ s,
                                                 float* __restrict__ pmax,
                                                 float* __restrict__ psum) {
    __shared__ __align__(16) char smem[16384];
    const int b = blockIdx.x;
    if (b < 628) gemm_tile(h, wt, s, b, smem);
    else         pool_part(h, pmax, psum, b - 628, smem);
}

// ---------- standalone pool (layer 3) ----------
__global__ __launch_bounds__(256) void pool_k(const ushort* __restrict__ h,
                                              float* __restrict__ pmax,
                                              float* __restrict__ psum) {
    __shared__ __align__(16) char smem[16384];
    pool_part(h, pmax, psum, blockIdx.x, smem);
}

// ---------- head MLP + log_softmax (1024 threads, split-k; proven) ----------
__global__ __launch_bounds__(1024) void mlp_k(const float* __restrict__ pool_max,
                                              const float* __restrict__ pool_sum,
                                              const float* __restrict__ l1W,
                                              const float* __restrict__ l1b,
                                              const float* __restrict__ l2W,
                                              const float* __restrict__ l2b,
                                              const float* __restrict__ l3W,
                                              const float* __restrict__ l3b,
                                              float* __restrict__ out) {
    __shared__ float g[1024];
    __shared__ float part[1024];
    __shared__ float a1[128];
    __shared__ float a2[64];
    __shared__ float a3[10];
    const int tid = threadIdx.x;
    if (tid < 512) {
        g[tid]       = pool_max[tid] + pool_max[512 + tid] + pool_max[1024 + tid];
        g[512 + tid] = (pool_sum[tid] + pool_sum[512 + tid] + pool_sum[1024 + tid]) *
                       (1.0f / N_NODES);
    }
    __syncthreads();
    {
        int ch = tid & 127, sl = tid >> 7;
        float acc = (sl == 0) ? l1b[ch] : 0.f;
        int k0 = sl * 128;
        #pragma unroll 4
        for (int k = k0; k < k0 + 128; ++k) acc += g[k] * l1W[k * 128 + ch];
        part[tid] = acc;
    }
    __syncthreads();
    if (tid < 128) {
        float a = part[tid];
        #pragma unroll
        for (int ss = 1; ss < 8; ++ss) a += part[tid + ss * 128];
        a1[tid] = fmaxf(a, 0.f);
    }
    __syncthreads();
    if (tid < 512) {
        int ch = tid & 63, sl = tid >> 6;
        float acc = (sl == 0) ? l2b[ch] : 0.f;
        int k0 = sl * 16;
        #pragma unroll
        for (int k = k0; k < k0 + 16; ++k) acc += a1[k] * l2W[k * 64 + ch];
        part[tid] = acc;
    }
    __syncthreads();
    if (tid < 64) {
        float a = part[tid];
        #pragma unroll
        for (int ss = 1; ss < 8; ++ss) a += part[tid + ss * 64];
        a2[tid] = fmaxf(a, 0.f);
    }
    __syncthreads();
    if (tid < 10) {
        float acc = l3b[tid];
        for (int k = 0; k < 64; ++k) acc += a2[k] * l3W[k * 10 + tid];
        a3[tid] = acc;
    }
    __syncthreads();
    if (tid == 0) {
        float m = a3[0];
        for (int j = 1; j < 10; ++j) m = fmaxf(m, a3[j]);
        float ssum = 0.f;
        for (int j = 0; j < 10; ++j) ssum += expf(a3[j] - m);
        float lse = m + logf(ssum);
        for (int j = 0; j < 10; ++j) out[j] = a3[j] - lse;
    }
}

extern "C" void kernel_launch(void* const* d_in, const int* in_sizes, int n_in,
                              void* d_out, int out_size, void* d_ws, size_t ws_size,
                              hipStream_t stream) {
    const float* x    = (const float*)d_in[0];
    const int*   rows = (const int*)  d_in[1];
    const int*   cols = (const int*)  d_in[2];
    const float* vals = (const float*)d_in[3];
    const float* W1   = (const float*)d_in[4];
    const float* b1   = (const float*)d_in[5];
    const float* W2   = (const float*)d_in[6];
    const float* b2   = (const float*)d_in[7];
    const float* W3   = (const float*)d_in[8];
    const float* b3   = (const float*)d_in[9];
    const float* l1W  = (const float*)d_in[10];
    const float* l1b  = (const float*)d_in[11];
    const float* l2W  = (const float*)d_in[12];
    const float* l2b  = (const float*)d_in[13];
    const float* l3W  = (const float*)d_in[14];
    const float* l3b  = (const float*)d_in[15];
    float* out = (float*)d_out;

    char* ws = (char*)d_ws;
    size_t off = 0;
    auto alloc = [&](size_t bytes) {
        void* p = ws + off;
        off += (bytes + 255) & ~(size_t)255;
        return p;
    };
    ushort* xb       = (ushort*)alloc((size_t)N_NODES * HD * 2);
    ushort* s        = (ushort*)alloc((size_t)N_NODES * HD * 2);
    ushort* hb       = (ushort*)alloc((size_t)N_NODES * HD * 2);
    ushort* wt1      = (ushort*)alloc((size_t)HD * HD * 2);
    ushort* wt2      = (ushort*)alloc((size_t)HD * HD * 2);
    ushort* wt3      = (ushort*)alloc((size_t)HD * HD * 2);
    int*    deg      = (int*)   alloc((size_t)N_NODES * 4);
    float*  pmax     = (float*) alloc((size_t)3 * 512 * 4);
    float*  psum     = (float*) alloc((size_t)3 * 512 * 4);
    int*    rowstart = (int*)   alloc((size_t)(N_NODES + 1) * 4);
    int*    cursor   = (int*)   alloc((size_t)N_NODES * 4);
    int2*   csr_cv   = (int2*)  alloc((size_t)N_EDGES * 8);
    (void)ws_size; (void)in_sizes; (void)n_in; (void)out_size;

    // 1: prep (cvt + wt + zero deg/pmax/psum)
    prep_k<<<NB_CVT + NB_WT + NB_ZD + 12, 256, 0, stream>>>(
        x, xb, W1, W2, W3, wt1, wt2, wt3, deg, pmax, psum);
    // 2: gemm1 || hist
    fused1_k<<<628 + 1250, 256, 0, stream>>>(xb, wt1, s, rows, deg);
    // 3: scan
    scan_k<<<1, 1024, 0, stream>>>(deg, rowstart, cursor);
    // 4: fill CSR
    fill_k<<<(N_EDGES + 255) / 256, 256, 0, stream>>>(rows, cols, vals, cursor,
                                                      csr_cv);
    const int AB = (N_NODES / 4) * 8;   // 5000 row-groups x 8 channel slices
    // 5: agg1
    agg_k<<<AB, 256, 0, stream>>>(s, rowstart, csr_cv, b1, hb);
    // 6: gemm2 || pool1
    fusedgp_k<<<628 + 256, 256, 0, stream>>>(hb, wt2, s, pmax, psum);
    // 7: agg2
    agg_k<<<AB, 256, 0, stream>>>(s, rowstart, csr_cv, b2, hb);
    // 8: gemm3 || pool2
    fusedgp_k<<<628 + 256, 256, 0, stream>>>(hb, wt3, s, pmax + 512, psum + 512);
    // 9: agg3
    agg_k<<<AB, 256, 0, stream>>>(s, rowstart, csr_cv, b3, hb);
    // 10: pool3
    pool_k<<<256, 256, 0, stream>>>(hb, pmax + 1024, psum + 1024);
    // 11: mlp head
    mlp_k<<<1, 1024, 0, stream>>>(pmax, psum, l1W, l1b, l2W, l2b, l3W, l3b, out);
}

// Round 3
// 436.109 us; speedup vs baseline: 1.2399x; 1.0085x over previous
//
#include <hip/hip_runtime.h>
#include <hip/hip_bf16.h>

#define N_NODES 20000
#define N_EDGES 320000
#define HD 512

typedef __attribute__((ext_vector_type(8))) short bf16x8;
typedef __attribute__((ext_vector_type(4))) float f32x4;

// ---------- bf16 helpers ----------
__device__ inline ushort f2bf(float f) {
    uint u = __float_as_uint(f);
    uint r = (u + 0x7fffu + ((u >> 16) & 1u)) >> 16;
    return (ushort)r;
}
__device__ inline uint pack2(float a, float b) {
    return (uint)f2bf(a) | ((uint)f2bf(b) << 16);
}
__device__ inline float bflo(uint u) { return __uint_as_float(u << 16); }
__device__ inline float bfhi(uint u) { return __uint_as_float(u & 0xffff0000u); }

__device__ __forceinline__ void async_load16(const void* g, void* l) {
    __builtin_amdgcn_global_load_lds(
        (const __attribute__((address_space(1))) uint*)g,
        (__attribute__((address_space(3))) uint*)l,
        16, 0, 0);
}

// ---------- gemm tile: 128x128, global_load_lds, XOR swizzle (proven) -------
__device__ __forceinline__ void gemm_tile(const ushort* __restrict__ A,
                                          const ushort* __restrict__ Bt,
                                          ushort* __restrict__ C,
                                          int tile, char* smem) {
    short* As = (short*)smem;
    short* Bs = (short*)(smem + 128 * 32 * 2);
    const int tid = threadIdx.x;
    const int lane = tid & 63;
    const int wave = tid >> 6;
    const int l15 = lane & 15;
    const int q = lane >> 4;
    const int wrow = wave >> 1, wcol = wave & 1;
    const int row0 = (tile >> 2) * 128;
    const int col0 = (tile & 3) * 128;

    const int srow = lane >> 2;
    const int kc   = (lane & 3) ^ ((lane >> 3) & 3);
    const int sl   = (l15 >> 1) & 3;

    f32x4 acc[4][4] = {};

    for (int k0 = 0; k0 < HD; k0 += 32) {
        #pragma unroll
        for (int l = 0; l < 2; ++l) {
            const int rbase = wave * 32 + l * 16;
            const ushort* ga = &A [(size_t)(row0 + rbase + srow) * HD + k0 + kc * 8];
            const ushort* gb = &Bt[(size_t)(col0 + rbase + srow) * HD + k0 + kc * 8];
            async_load16(ga, &As[rbase * 32]);
            async_load16(gb, &Bs[rbase * 32]);
        }
        __syncthreads();
        bf16x8 aF[4], bF[4];
        #pragma unroll
        for (int i = 0; i < 4; ++i)
            aF[i] = *(bf16x8*)&As[(wrow * 64 + i * 16 + l15) * 32 + (q ^ sl) * 8];
        #pragma unroll
        for (int j = 0; j < 4; ++j)
            bF[j] = *(bf16x8*)&Bs[(wcol * 64 + j * 16 + l15) * 32 + (q ^ sl) * 8];
        #pragma unroll
        for (int i = 0; i < 4; ++i)
            #pragma unroll
            for (int j = 0; j < 4; ++j)
                acc[i][j] = __builtin_amdgcn_mfma_f32_16x16x32_bf16(aF[i], bF[j], acc[i][j], 0, 0, 0);
        __syncthreads();
    }
    #pragma unroll
    for (int i = 0; i < 4; ++i) {
        #pragma unroll
        for (int r = 0; r < 4; ++r) {
            int gr = row0 + wrow * 64 + i * 16 + q * 4 + r;
            if (gr < N_NODES) {
                #pragma unroll
                for (int j = 0; j < 4; ++j) {
                    int gc = col0 + wcol * 64 + j * 16 + l15;
                    C[(size_t)gr * HD + gc] = f2bf(acc[i][j][r]);
                }
            }
        }
    }
}

// ---------- pool partial (proven) ----------
__device__ __forceinline__ void pool_part(const ushort* __restrict__ h,
                                          float* __restrict__ pmax,
                                          float* __restrict__ psum,
                                          int pb, char* smem) {
    float* lmx = (float*)smem;           // 2048 floats
    float* lsm = lmx + 2048;             // 2048 floats
    const int tid = threadIdx.x;
    const int wave = tid >> 6, lane = tid & 63;
    const uint4* h4 = (const uint4*)h;
    float m[8] = {}, sm[8] = {};
    for (int r = pb * 4 + wave; r < N_NODES; r += 1024) {
        uint4 v = h4[(size_t)r * 64 + lane];
        m[0] = fmaxf(m[0], bflo(v.x)); sm[0] += bflo(v.x);
        m[1] = fmaxf(m[1], bfhi(v.x)); sm[1] += bfhi(v.x);
        m[2] = fmaxf(m[2], bflo(v.y)); sm[2] += bflo(v.y);
        m[3] = fmaxf(m[3], bfhi(v.y)); sm[3] += bfhi(v.y);
        m[4] = fmaxf(m[4], bflo(v.z)); sm[4] += bflo(v.z);
        m[5] = fmaxf(m[5], bfhi(v.z)); sm[5] += bfhi(v.z);
        m[6] = fmaxf(m[6], bflo(v.w)); sm[6] += bflo(v.w);
        m[7] = fmaxf(m[7], bfhi(v.w)); sm[7] += bfhi(v.w);
    }
    #pragma unroll
    for (int i = 0; i < 8; ++i) {
        lmx[wave * 512 + lane * 8 + i] = m[i];
        lsm[wave * 512 + lane * 8 + i] = sm[i];
    }
    __syncthreads();
    #pragma unroll
    for (int cc = 0; cc < 2; ++cc) {
        int ch = tid * 2 + cc;
        float mx = fmaxf(fmaxf(lmx[ch], lmx[512 + ch]),
                         fmaxf(lmx[1024 + ch], lmx[1536 + ch]));
        float sv = (lsm[ch] + lsm[512 + ch]) + (lsm[1024 + ch] + lsm[1536 + ch]);
        atomicMax((int*)&pmax[ch], __float_as_int(mx));   // values >= 0
        atomicAdd(&psum[ch], sv);
    }
}

// ---------- prep: cvt x | wt transpose | zero deg/pmax/psum ----------
#define NB_CVT 5000
#define NB_WT  192
#define NB_ZD  79
__global__ __launch_bounds__(256) void prep_k(const float* __restrict__ x,
                                              ushort* __restrict__ xb,
                                              const float* __restrict__ W1,
                                              const float* __restrict__ W2,
                                              const float* __restrict__ W3,
                                              ushort* __restrict__ T1,
                                              ushort* __restrict__ T2,
                                              ushort* __restrict__ T3,
                                              int* __restrict__ deg,
                                              float* __restrict__ pmax,
                                              float* __restrict__ psum) {
    __shared__ float t[64][65];
    const int b = blockIdx.x;
    const int tid = threadIdx.x;
    if (b < NB_CVT) {
        int c = b * 256 + tid;
        const float4* p = (const float4*)x + (size_t)c * 2;
        float4 a = p[0], q = p[1];
        uint4 o;
        o.x = pack2(a.x, a.y); o.y = pack2(a.z, a.w);
        o.z = pack2(q.x, q.y); o.w = pack2(q.z, q.w);
        ((uint4*)xb)[c] = o;
    } else if (b < NB_CVT + NB_WT) {
        int idx = b - NB_CVT;
        int layer = idx >> 6, rem = idx & 63;
        const float* W = (layer == 0) ? W1 : (layer == 1) ? W2 : W3;
        ushort* T      = (layer == 0) ? T1 : (layer == 1) ? T2 : T3;
        int kb = (rem >> 3) * 64, nb = (rem & 7) * 64;
        int c = tid & 63, r4 = tid >> 6;
        #pragma unroll
        for (int l = 0; l < 16; ++l) {
            int r = l * 4 + r4;
            t[r][c] = W[(size_t)(kb + r) * HD + nb + c];
        }
        __syncthreads();
        #pragma unroll
        for (int l = 0; l < 16; ++l) {
            int r = l * 4 + r4;
            T[(size_t)(nb + r) * HD + kb + c] = f2bf(t[c][r]);
        }
    } else if (b < NB_CVT + NB_WT + NB_ZD) {
        int i = (b - NB_CVT - NB_WT) * 256 + tid;
        if (i < N_NODES) deg[i] = 0;
    } else if (b < NB_CVT + NB_WT + NB_ZD + 6) {
        int i = (b - NB_CVT - NB_WT - NB_ZD) * 256 + tid;
        pmax[i] = 0.f;
    } else {
        int i = (b - NB_CVT - NB_WT - NB_ZD - 6) * 256 + tid;
        psum[i] = 0.f;
    }
}

// ---------- fused1: gemm layer1 (0..627) || hist (628..1877) ----------
__global__ __launch_bounds__(256) void fused1_k(const ushort* __restrict__ xb,
                                                const ushort* __restrict__ wt1,
                                                ushort* __restrict__ s,
                                                const int* __restrict__ rows,
                                                int* __restrict__ deg) {
    __shared__ __align__(16) char smem[16384];
    const int b = blockIdx.x;
    if (b < 628) {
        gemm_tile(xb, wt1, s, b, smem);
    } else {
        int e = (b - 628) * 256 + threadIdx.x;   // 1250*256 == N_EDGES exactly
        atomicAdd(&deg[rows[e]], 1);
    }
}

// ---------- scan: one workgroup, 16 waves, shuffle (proven ~4 µs) ----------
__global__ __launch_bounds__(1024) void scan_k(const int* __restrict__ deg,
                                               int* __restrict__ rowstart,
                                               int* __restrict__ cursor) {
    __shared__ int wsum[16];
    const int tid = threadIdx.x;
    const int lane = tid & 63, wv = tid >> 6;
    int carry = 0;
    for (int base = 0; base < N_NODES; base += 1024) {
        int i = base + tid;
        int v = (i < N_NODES) ? deg[i] : 0;
        int incl = v;
        #pragma unroll
        for (int off = 1; off < 64; off <<= 1) {
            int t = __shfl_up(incl, off, 64);
            if (lane >= off) incl += t;
        }
        if (lane == 63) wsum[wv] = incl;
        __syncthreads();
        int woff = 0, tot = 0;
        #pragma unroll
        for (int w = 0; w < 16; ++w) {
            int sv = wsum[w];
            if (w < wv) woff += sv;
            tot += sv;
        }
        if (i < N_NODES) {
            int ex = carry + woff + incl - v;
            rowstart[i] = ex;
            cursor[i]   = ex;
        }
        carry += tot;
        __syncthreads();
    }
    if (tid == 0) rowstart[N_NODES] = carry;
}

// ---------- fill CSR (col+val packed into int2 -> one 8B load in agg) ------
__global__ void fill_k(const int* __restrict__ rows, const int* __restrict__ cols,
                       const float* __restrict__ vals, int* __restrict__ cursor,
                       int2* __restrict__ csr_cv) {
    int e = blockIdx.x * blockDim.x + threadIdx.x;
    if (e < N_EDGES) {
        int p = atomicAdd(&cursor[rows[e]], 1);
        csr_cv[p] = make_int2(cols[e], __float_as_int(vals[e]));
    }
}

// ---------- aggregate v3: sliced + XCD-pinned + 20 rows/wave ---------------
// r2 post-mortem: gathers were L2-resident (FETCH 21 MB) but each wave owned
// ONE row (~16 edges): wave lifetime = serial chain {2x rowstart load,
// metadata, gather, 24-op reduce} ~3000 cy for 2 KB gathered -> latency-bound
// at 5.1 TB/s vs 34.5 TB/s L2 ceiling. Fix: 20 contiguous rows per wave,
// 2000 blocks (250/slice). All 21 row bounds fetched by ONE wave load +
// shfl; bias hoisted; inner loop keeps 2 gathers in flight and now has ~26
// iterations of runway per wave, so loads pipeline across rows.
__device__ inline void fma8(float* acc, uint4 v, float w) {
    acc[0] += w * bflo(v.x); acc[1] += w * bfhi(v.x);
    acc[2] += w * bflo(v.y); acc[3] += w * bfhi(v.y);
    acc[4] += w * bflo(v.z); acc[5] += w * bfhi(v.z);
    acc[6] += w * bflo(v.w); acc[7] += w * bfhi(v.w);
}

#define ROWS_PER_WAVE 20
#define ROWS_PER_BLOCK 80
#define AGG_BLOCKS (8 * (N_NODES / ROWS_PER_BLOCK))   // 2000

__global__ __launch_bounds__(256) void agg_k(const ushort* __restrict__ s,
                                             const int* __restrict__ rowstart,
                                             const int2* __restrict__ csr_cv,
                                             const float* __restrict__ bias,
                                             ushort* __restrict__ hout) {
    const int slice = blockIdx.x & 7;          // XCD-pinned channel slice
    const int chunk = blockIdx.x >> 3;         // 0..249
    const int wave = threadIdx.x >> 6, lane = threadIdx.x & 63;
    const int g = lane >> 3, sub = lane & 7;   // edge-group, 16B channel chunk
    const int rbase = chunk * ROWS_PER_BLOCK + wave * ROWS_PER_WAVE;
    const uint4* s4 = (const uint4*)s;
    const size_t sbase = (size_t)slice * 8 + sub;
    // all 21 row bounds with one wave-wide load
    const int rsv = rowstart[rbase + (lane < ROWS_PER_WAVE + 1 ? lane : ROWS_PER_WAVE)];
    // bias for this lane's 8 channels, hoisted out of the row loop
    const float4 b0 = ((const float4*)bias)[slice * 16 + sub * 2];
    const float4 b1 = ((const float4*)bias)[slice * 16 + sub * 2 + 1];

    for (int i = 0; i < ROWS_PER_WAVE; ++i) {
        const int beg = __shfl(rsv, i, 64);
        const int end = __shfl(rsv, i + 1, 64);
        float acc[8] = {};
        for (int j = beg; j < end; j += 16) {  // 16 edges, 2 gathers in flight
            int  e0 = j + g,      e1 = j + 8 + g;
            bool a0 = e0 < end,   a1 = e1 < end;
            int2 cv0 = csr_cv[a0 ? e0 : beg];
            int2 cv1 = csr_cv[a1 ? e1 : beg];
            uint4 v0 = s4[(size_t)cv0.x * 64 + sbase];
            uint4 v1 = s4[(size_t)cv1.x * 64 + sbase];
            fma8(acc, v0, a0 ? __int_as_float(cv0.y) : 0.f);
            fma8(acc, v1, a1 ? __int_as_float(cv1.y) : 0.f);
        }
        #pragma unroll
        for (int off = 8; off <= 32; off <<= 1)   // reduce across 8 edge-groups
            #pragma unroll
            for (int k = 0; k < 8; ++k)
                acc[k] += __shfl_xor(acc[k], off, 64);
        if (g == 0) {                          // lanes 0..7 own chunk `sub`
            const int r = rbase + i;
            uint4 ov;
            ov.x = pack2(fmaxf(acc[0] + b0.x, 0.f), fmaxf(acc[1] + b0.y, 0.f));
            ov.y = pack2(fmaxf(acc[2] + b0.z, 0.f), fmaxf(acc[3] + b0.w, 0.f));
            ov.z = pack2(fmaxf(acc[4] + b1.x, 0.f), fmaxf(acc[5] + b1.y, 0.f));
            ov.w = pack2(fmaxf(acc[6] + b1.z, 0.f), fmaxf(acc[7] + b1.w, 0.f));
            ((uint4*)hout)[(size_t)r * 64 + slice * 8 + sub] = ov;
        }
    }
}

// ---------- fused gemm || pool (both read-only on h; proven) ----------
__global__ __launch_bounds__(256) void fusedgp_k(const ushort* __restrict__ h,
                                                 const ushort* __restrict__ wt,
                                                 ushort* __restrict__ s,
                                                 float* __restrict__ pmax,
                                                 float* __restrict__ psum) {
    __shared__ __align__(16) char smem[16384];
    const int b = blockIdx.x;
    if (b < 628) gemm_tile(h, wt, s, b, smem);
    else         pool_part(h, pmax, psum, b - 628, smem);
}

// ---------- standalone pool (layer 3) ----------
__global__ __launch_bounds__(256) void pool_k(const ushort* __restrict__ h,
                                              float* __restrict__ pmax,
                                              float* __restrict__ psum) {
    __shared__ __align__(16) char smem[16384];
    pool_part(h, pmax, psum, blockIdx.x, smem);
}

// ---------- head MLP + log_softmax (1024 threads, split-k; proven) ----------
__global__ __launch_bounds__(1024) void mlp_k(const float* __restrict__ pool_max,
                                              const float* __restrict__ pool_sum,
                                              const float* __restrict__ l1W,
                                              const float* __restrict__ l1b,
                                              const float* __restrict__ l2W,
                                              const float* __restrict__ l2b,
                                              const float* __restrict__ l3W,
                                              const float* __restrict__ l3b,
                                              float* __restrict__ out) {
    __shared__ float g[1024];
    __shared__ float part[1024];
    __shared__ float a1[128];
    __shared__ float a2[64];
    __shared__ float a3[10];
    const int tid = threadIdx.x;
    if (tid < 512) {
        g[tid]       = pool_max[tid] + pool_max[512 + tid] + pool_max[1024 + tid];
        g[512 + tid] = (pool_sum[tid] + pool_sum[512 + tid] + pool_sum[1024 + tid]) *
                       (1.0f / N_NODES);
    }
    __syncthreads();
    {
        int ch = tid & 127, sl = tid >> 7;
        float acc = (sl == 0) ? l1b[ch] : 0.f;
        int k0 = sl * 128;
        #pragma unroll 4
        for (int k = k0; k < k0 + 128; ++k) acc += g[k] * l1W[k * 128 + ch];
        part[tid] = acc;
    }
    __syncthreads();
    if (tid < 128) {
        float a = part[tid];
        #pragma unroll
        for (int ss = 1; ss < 8; ++ss) a += part[tid + ss * 128];
        a1[tid] = fmaxf(a, 0.f);
    }
    __syncthreads();
    if (tid < 512) {
        int ch = tid & 63, sl = tid >> 6;
        float acc = (sl == 0) ? l2b[ch] : 0.f;
        int k0 = sl * 16;
        #pragma unroll
        for (int k = k0; k < k0 + 16; ++k) acc += a1[k] * l2W[k * 64 + ch];
        part[tid] = acc;
    }
    __syncthreads();
    if (tid < 64) {
        float a = part[tid];
        #pragma unroll
        for (int ss = 1; ss < 8; ++ss) a += part[tid + ss * 64];
        a2[tid] = fmaxf(a, 0.f);
    }
    __syncthreads();
    if (tid < 10) {
        float acc = l3b[tid];
        for (int k = 0; k < 64; ++k) acc += a2[k] * l3W[k * 10 + tid];
        a3[tid] = acc;
    }
    __syncthreads();
    if (tid == 0) {
        float m = a3[0];
        for (int j = 1; j < 10; ++j) m = fmaxf(m, a3[j]);
        float ssum = 0.f;
        for (int j = 0; j < 10; ++j) ssum += expf(a3[j] - m);
        float lse = m + logf(ssum);
        for (int j = 0; j < 10; ++j) out[j] = a3[j] - lse;
    }
}

extern "C" void kernel_launch(void* const* d_in, const int* in_sizes, int n_in,
                              void* d_out, int out_size, void* d_ws, size_t ws_size,
                              hipStream_t stream) {
    const float* x    = (const float*)d_in[0];
    const int*   rows = (const int*)  d_in[1];
    const int*   cols = (const int*)  d_in[2];
    const float* vals = (const float*)d_in[3];
    const float* W1   = (const float*)d_in[4];
    const float* b1   = (const float*)d_in[5];
    const float* W2   = (const float*)d_in[6];
    const float* b2   = (const float*)d_in[7];
    const float* W3   = (const float*)d_in[8];
    const float* b3   = (const float*)d_in[9];
    const float* l1W  = (const float*)d_in[10];
    const float* l1b  = (const float*)d_in[11];
    const float* l2W  = (const float*)d_in[12];
    const float* l2b  = (const float*)d_in[13];
    const float* l3W  = (const float*)d_in[14];
    const float* l3b  = (const float*)d_in[15];
    float* out = (float*)d_out;

    char* ws = (char*)d_ws;
    size_t off = 0;
    auto alloc = [&](size_t bytes) {
        void* p = ws + off;
        off += (bytes + 255) & ~(size_t)255;
        return p;
    };
    ushort* xb       = (ushort*)alloc((size_t)N_NODES * HD * 2);
    ushort* s        = (ushort*)alloc((size_t)N_NODES * HD * 2);
    ushort* hb       = (ushort*)alloc((size_t)N_NODES * HD * 2);
    ushort* wt1      = (ushort*)alloc((size_t)HD * HD * 2);
    ushort* wt2      = (ushort*)alloc((size_t)HD * HD * 2);
    ushort* wt3      = (ushort*)alloc((size_t)HD * HD * 2);
    int*    deg      = (int*)   alloc((size_t)N_NODES * 4);
    float*  pmax     = (float*) alloc((size_t)3 * 512 * 4);
    float*  psum     = (float*) alloc((size_t)3 * 512 * 4);
    int*    rowstart = (int*)   alloc((size_t)(N_NODES + 1) * 4);
    int*    cursor   = (int*)   alloc((size_t)N_NODES * 4);
    int2*   csr_cv   = (int2*)  alloc((size_t)N_EDGES * 8);
    (void)ws_size; (void)in_sizes; (void)n_in; (void)out_size;

    // 1: prep (cvt + wt + zero deg/pmax/psum)
    prep_k<<<NB_CVT + NB_WT + NB_ZD + 12, 256, 0, stream>>>(
        x, xb, W1, W2, W3, wt1, wt2, wt3, deg, pmax, psum);
    // 2: gemm1 || hist
    fused1_k<<<628 + 1250, 256, 0, stream>>>(xb, wt1, s, rows, deg);
    // 3: scan
    scan_k<<<1, 1024, 0, stream>>>(deg, rowstart, cursor);
    // 4: fill CSR
    fill_k<<<(N_EDGES + 255) / 256, 256, 0, stream>>>(rows, cols, vals, cursor,
                                                      csr_cv);
    // 5: agg1
    agg_k<<<AGG_BLOCKS, 256, 0, stream>>>(s, rowstart, csr_cv, b1, hb);
    // 6: gemm2 || pool1
    fusedgp_k<<<628 + 256, 256, 0, stream>>>(hb, wt2, s, pmax, psum);
    // 7: agg2
    agg_k<<<AGG_BLOCKS, 256, 0, stream>>>(s, rowstart, csr_cv, b2, hb);
    // 8: gemm3 || pool2
    fusedgp_k<<<628 + 256, 256, 0, stream>>>(hb, wt3, s, pmax + 512, psum + 512);
    // 9: agg3
    agg_k<<<AGG_BLOCKS, 256, 0, stream>>>(s, rowstart, csr_cv, b3, hb);
    // 10: pool3
    pool_k<<<256, 256, 0, stream>>>(hb, pmax + 1024, psum + 1024);
    // 11: mlp head
    mlp_k<<<1, 1024, 0, stream>>>(pmax, psum, l1W, l1b, l2W, l2b, l3W, l3b, out);
}

// Round 4
// 416.401 us; speedup vs baseline: 1.2985x; 1.0473x over previous
//
#include <hip/hip_runtime.h>
#include <hip/hip_bf16.h>

#define N_NODES 20000
#define N_EDGES 320000
#define HD 512

typedef __attribute__((ext_vector_type(8))) short bf16x8;
typedef __attribute__((ext_vector_type(4))) float f32x4;

// ---------- bf16 helpers ----------
__device__ inline ushort f2bf(float f) {
    uint u = __float_as_uint(f);
    uint r = (u + 0x7fffu + ((u >> 16) & 1u)) >> 16;
    return (ushort)r;
}
__device__ inline uint pack2(float a, float b) {
    return (uint)f2bf(a) | ((uint)f2bf(b) << 16);
}
__device__ inline float bflo(uint u) { return __uint_as_float(u << 16); }
__device__ inline float bfhi(uint u) { return __uint_as_float(u & 0xffff0000u); }

__device__ __forceinline__ void async_load16(const void* g, void* l) {
    __builtin_amdgcn_global_load_lds(
        (const __attribute__((address_space(1))) uint*)g,
        (__attribute__((address_space(3))) uint*)l,
        16, 0, 0);
}

// ---------- gemm tile: 128x128, global_load_lds, XOR swizzle (proven) -------
__device__ __forceinline__ void gemm_tile(const ushort* __restrict__ A,
                                          const ushort* __restrict__ Bt,
                                          ushort* __restrict__ C,
                                          int tile, char* smem) {
    short* As = (short*)smem;
    short* Bs = (short*)(smem + 128 * 32 * 2);
    const int tid = threadIdx.x;
    const int lane = tid & 63;
    const int wave = tid >> 6;
    const int l15 = lane & 15;
    const int q = lane >> 4;
    const int wrow = wave >> 1, wcol = wave & 1;
    const int row0 = (tile >> 2) * 128;
    const int col0 = (tile & 3) * 128;

    const int srow = lane >> 2;
    const int kc   = (lane & 3) ^ ((lane >> 3) & 3);
    const int sl   = (l15 >> 1) & 3;

    f32x4 acc[4][4] = {};

    for (int k0 = 0; k0 < HD; k0 += 32) {
        #pragma unroll
        for (int l = 0; l < 2; ++l) {
            const int rbase = wave * 32 + l * 16;
            const ushort* ga = &A [(size_t)(row0 + rbase + srow) * HD + k0 + kc * 8];
            const ushort* gb = &Bt[(size_t)(col0 + rbase + srow) * HD + k0 + kc * 8];
            async_load16(ga, &As[rbase * 32]);
            async_load16(gb, &Bs[rbase * 32]);
        }
        __syncthreads();
        bf16x8 aF[4], bF[4];
        #pragma unroll
        for (int i = 0; i < 4; ++i)
            aF[i] = *(bf16x8*)&As[(wrow * 64 + i * 16 + l15) * 32 + (q ^ sl) * 8];
        #pragma unroll
        for (int j = 0; j < 4; ++j)
            bF[j] = *(bf16x8*)&Bs[(wcol * 64 + j * 16 + l15) * 32 + (q ^ sl) * 8];
        #pragma unroll
        for (int i = 0; i < 4; ++i)
            #pragma unroll
            for (int j = 0; j < 4; ++j)
                acc[i][j] = __builtin_amdgcn_mfma_f32_16x16x32_bf16(aF[i], bF[j], acc[i][j], 0, 0, 0);
        __syncthreads();
    }
    #pragma unroll
    for (int i = 0; i < 4; ++i) {
        #pragma unroll
        for (int r = 0; r < 4; ++r) {
            int gr = row0 + wrow * 64 + i * 16 + q * 4 + r;
            if (gr < N_NODES) {
                #pragma unroll
                for (int j = 0; j < 4; ++j) {
                    int gc = col0 + wcol * 64 + j * 16 + l15;
                    C[(size_t)gr * HD + gc] = f2bf(acc[i][j][r]);
                }
            }
        }
    }
}

// ---------- pool partial (proven) ----------
__device__ __forceinline__ void pool_part(const ushort* __restrict__ h,
                                          float* __restrict__ pmax,
                                          float* __restrict__ psum,
                                          int pb, char* smem) {
    float* lmx = (float*)smem;           // 2048 floats
    float* lsm = lmx + 2048;             // 2048 floats
    const int tid = threadIdx.x;
    const int wave = tid >> 6, lane = tid & 63;
    const uint4* h4 = (const uint4*)h;
    float m[8] = {}, sm[8] = {};
    for (int r = pb * 4 + wave; r < N_NODES; r += 1024) {
        uint4 v = h4[(size_t)r * 64 + lane];
        m[0] = fmaxf(m[0], bflo(v.x)); sm[0] += bflo(v.x);
        m[1] = fmaxf(m[1], bfhi(v.x)); sm[1] += bfhi(v.x);
        m[2] = fmaxf(m[2], bflo(v.y)); sm[2] += bflo(v.y);
        m[3] = fmaxf(m[3], bfhi(v.y)); sm[3] += bfhi(v.y);
        m[4] = fmaxf(m[4], bflo(v.z)); sm[4] += bflo(v.z);
        m[5] = fmaxf(m[5], bfhi(v.z)); sm[5] += bfhi(v.z);
        m[6] = fmaxf(m[6], bflo(v.w)); sm[6] += bflo(v.w);
        m[7] = fmaxf(m[7], bfhi(v.w)); sm[7] += bfhi(v.w);
    }
    #pragma unroll
    for (int i = 0; i < 8; ++i) {
        lmx[wave * 512 + lane * 8 + i] = m[i];
        lsm[wave * 512 + lane * 8 + i] = sm[i];
    }
    __syncthreads();
    #pragma unroll
    for (int cc = 0; cc < 2; ++cc) {
        int ch = tid * 2 + cc;
        float mx = fmaxf(fmaxf(lmx[ch], lmx[512 + ch]),
                         fmaxf(lmx[1024 + ch], lmx[1536 + ch]));
        float sv = (lsm[ch] + lsm[512 + ch]) + (lsm[1024 + ch] + lsm[1536 + ch]);
        atomicMax((int*)&pmax[ch], __float_as_int(mx));   // values >= 0
        atomicAdd(&psum[ch], sv);
    }
}

// ---------- prep: cvt x | wt transpose | zero deg/pmax/psum ----------
#define NB_CVT 5000
#define NB_WT  192
#define NB_ZD  79
__global__ __launch_bounds__(256) void prep_k(const float* __restrict__ x,
                                              ushort* __restrict__ xb,
                                              const float* __restrict__ W1,
                                              const float* __restrict__ W2,
                                              const float* __restrict__ W3,
                                              ushort* __restrict__ T1,
                                              ushort* __restrict__ T2,
                                              ushort* __restrict__ T3,
                                              int* __restrict__ deg,
                                              float* __restrict__ pmax,
                                              float* __restrict__ psum) {
    __shared__ float t[64][65];
    const int b = blockIdx.x;
    const int tid = threadIdx.x;
    if (b < NB_CVT) {
        int c = b * 256 + tid;
        const float4* p = (const float4*)x + (size_t)c * 2;
        float4 a = p[0], q = p[1];
        uint4 o;
        o.x = pack2(a.x, a.y); o.y = pack2(a.z, a.w);
        o.z = pack2(q.x, q.y); o.w = pack2(q.z, q.w);
        ((uint4*)xb)[c] = o;
    } else if (b < NB_CVT + NB_WT) {
        int idx = b - NB_CVT;
        int layer = idx >> 6, rem = idx & 63;
        const float* W = (layer == 0) ? W1 : (layer == 1) ? W2 : W3;
        ushort* T      = (layer == 0) ? T1 : (layer == 1) ? T2 : T3;
        int kb = (rem >> 3) * 64, nb = (rem & 7) * 64;
        int c = tid & 63, r4 = tid >> 6;
        #pragma unroll
        for (int l = 0; l < 16; ++l) {
            int r = l * 4 + r4;
            t[r][c] = W[(size_t)(kb + r) * HD + nb + c];
        }
        __syncthreads();
        #pragma unroll
        for (int l = 0; l < 16; ++l) {
            int r = l * 4 + r4;
            T[(size_t)(nb + r) * HD + kb + c] = f2bf(t[c][r]);
        }
    } else if (b < NB_CVT + NB_WT + NB_ZD) {
        int i = (b - NB_CVT - NB_WT) * 256 + tid;
        if (i < N_NODES) deg[i] = 0;
    } else if (b < NB_CVT + NB_WT + NB_ZD + 6) {
        int i = (b - NB_CVT - NB_WT - NB_ZD) * 256 + tid;
        pmax[i] = 0.f;
    } else {
        int i = (b - NB_CVT - NB_WT - NB_ZD - 6) * 256 + tid;
        psum[i] = 0.f;
    }
}

// ---------- fused1: gemm layer1 (0..627) || hist (628..1877) ----------
__global__ __launch_bounds__(256) void fused1_k(const ushort* __restrict__ xb,
                                                const ushort* __restrict__ wt1,
                                                ushort* __restrict__ s,
                                                const int* __restrict__ rows,
                                                int* __restrict__ deg) {
    __shared__ __align__(16) char smem[16384];
    const int b = blockIdx.x;
    if (b < 628) {
        gemm_tile(xb, wt1, s, b, smem);
    } else {
        int e = (b - 628) * 256 + threadIdx.x;   // 1250*256 == N_EDGES exactly
        atomicAdd(&deg[rows[e]], 1);
    }
}

// ---------- scan: one workgroup, 16 waves, shuffle (proven ~4 µs) ----------
__global__ __launch_bounds__(1024) void scan_k(const int* __restrict__ deg,
                                               int* __restrict__ rowstart,
                                               int* __restrict__ cursor) {
    __shared__ int wsum[16];
    const int tid = threadIdx.x;
    const int lane = tid & 63, wv = tid >> 6;
    int carry = 0;
    for (int base = 0; base < N_NODES; base += 1024) {
        int i = base + tid;
        int v = (i < N_NODES) ? deg[i] : 0;
        int incl = v;
        #pragma unroll
        for (int off = 1; off < 64; off <<= 1) {
            int t = __shfl_up(incl, off, 64);
            if (lane >= off) incl += t;
        }
        if (lane == 63) wsum[wv] = incl;
        __syncthreads();
        int woff = 0, tot = 0;
        #pragma unroll
        for (int w = 0; w < 16; ++w) {
            int sv = wsum[w];
            if (w < wv) woff += sv;
            tot += sv;
        }
        if (i < N_NODES) {
            int ex = carry + woff + incl - v;
            rowstart[i] = ex;
            cursor[i]   = ex;
        }
        carry += tot;
        __syncthreads();
    }
    if (tid == 0) rowstart[N_NODES] = carry;
}

// ---------- fill CSR (col+val packed into int2 -> one 8B load in agg) ------
__global__ void fill_k(const int* __restrict__ rows, const int* __restrict__ cols,
                       const float* __restrict__ vals, int* __restrict__ cursor,
                       int2* __restrict__ csr_cv) {
    int e = blockIdx.x * blockDim.x + threadIdx.x;
    if (e < N_EDGES) {
        int p = atomicAdd(&cursor[rows[e]], 1);
        csr_cv[p] = make_int2(cols[e], __float_as_int(vals[e]));
    }
}

// ---------- aggregate v4: sliced + XCD-pinned + group-owns-row (NO shuffle) -
// r3 post-mortem: r2/r3's cost was the per-row-slice butterfly: 24 ds_bpermute
// x 160K row-slices ~ 3.8M DS instrs @ ~5.8cy/CU = ~36us of serialized LDS-pipe
// time, invariant across r2/r3 (why both measured ~65us). Fix: each 8-lane
// group owns its rows outright -- lane (g,sub) accumulates 8 channels of
// group g's current row in registers. Zero shuffles / LDS / atomics.
// Per edge: 1 group-uniform 8B meta load + 1 coalesced 128B gather + fma8.
// Group g streams 5 contiguous rows (sequential metadata, ~640B). Row done ->
// its 8 lanes store 128B (bias+relu fused). Degree-0 rows store relu(bias).
// 2-edge unroll keeps 4 VMEM in flight/wave. Slicing (L2-resident, FETCH
// 21MB) and XCD pinning carried over unchanged.
__device__ inline void fma8(float* acc, uint4 v, float w) {
    acc[0] += w * bflo(v.x); acc[1] += w * bfhi(v.x);
    acc[2] += w * bflo(v.y); acc[3] += w * bfhi(v.y);
    acc[4] += w * bflo(v.z); acc[5] += w * bfhi(v.z);
    acc[6] += w * bflo(v.w); acc[7] += w * bfhi(v.w);
}

#define RPG 5                                   // rows per 8-lane group
#define AGG_RPB (32 * RPG)                      // 160 rows per block
#define AGG_BLOCKS (8 * (N_NODES / AGG_RPB))    // 8 slices * 125 = 1000

__global__ __launch_bounds__(256) void agg_k(const ushort* __restrict__ s,
                                             const int* __restrict__ rowstart,
                                             const int2* __restrict__ csr_cv,
                                             const float* __restrict__ bias,
                                             ushort* __restrict__ hout) {
    const int slice = blockIdx.x & 7;           // XCD-pinned channel slice
    const int cidx  = blockIdx.x >> 3;          // 0..124
    const int wave = threadIdx.x >> 6, lane = threadIdx.x & 63;
    const int g = lane >> 3, sub = lane & 7;    // group, 16B channel chunk
    const uint4* s4 = (const uint4*)s;
    const size_t sbase = (size_t)slice * 8 + sub;
    uint4* houtp = (uint4*)hout + slice * 8 + sub;
    const float4 b0 = ((const float4*)bias)[slice * 16 + sub * 2];
    const float4 b1 = ((const float4*)bias)[slice * 16 + sub * 2 + 1];

    int r = cidx * AGG_RPB + wave * (8 * RPG) + g * RPG;
    const int rend = r + RPG;
    int j   = rowstart[r];                      // group-uniform
    int end = rowstart[r + 1];
    float acc[8] = {};
    for (;;) {
        if (j < end) {
            int  j1 = j + 1;
            bool t2 = j1 < end;
            int2 cv0 = csr_cv[j];
            int2 cv1 = csr_cv[t2 ? j1 : j];
            uint4 v0 = s4[(size_t)cv0.x * 64 + sbase];
            uint4 v1 = s4[(size_t)cv1.x * 64 + sbase];
            fma8(acc, v0, __int_as_float(cv0.y));
            fma8(acc, v1, t2 ? __int_as_float(cv1.y) : 0.f);
            j += t2 ? 2 : 1;
        } else {
            uint4 ov;                           // flush row r (8 lanes = 128B)
            ov.x = pack2(fmaxf(acc[0] + b0.x, 0.f), fmaxf(acc[1] + b0.y, 0.f));
            ov.y = pack2(fmaxf(acc[2] + b0.z, 0.f), fmaxf(acc[3] + b0.w, 0.f));
            ov.z = pack2(fmaxf(acc[4] + b1.x, 0.f), fmaxf(acc[5] + b1.y, 0.f));
            ov.w = pack2(fmaxf(acc[6] + b1.z, 0.f), fmaxf(acc[7] + b1.w, 0.f));
            houtp[(size_t)r * 64] = ov;
            if (++r >= rend) break;
            end = rowstart[r + 1];              // j already == new row start
            #pragma unroll
            for (int k = 0; k < 8; ++k) acc[k] = 0.f;
        }
    }
}

// ---------- fused gemm || pool (both read-only on h; proven) ----------
__global__ __launch_bounds__(256) void fusedgp_k(const ushort* __restrict__ h,
                                                 const ushort* __restrict__ wt,
                                                 ushort* __restrict__ s,
                                                 float* __restrict__ pmax,
                                                 float* __restrict__ psum) {
    __shared__ __align__(16) char smem[16384];
    const int b = blockIdx.x;
    if (b < 628) gemm_tile(h, wt, s, b, smem);
    else         pool_part(h, pmax, psum, b - 628, smem);
}

// ---------- standalone pool (layer 3) ----------
__global__ __launch_bounds__(256) void pool_k(const ushort* __restrict__ h,
                                              float* __restrict__ pmax,
                                              float* __restrict__ psum) {
    __shared__ __align__(16) char smem[16384];
    pool_part(h, pmax, psum, blockIdx.x, smem);
}

// ---------- head MLP + log_softmax (1024 threads, split-k; proven) ----------
__global__ __launch_bounds__(1024) void mlp_k(const float* __restrict__ pool_max,
                                              const float* __restrict__ pool_sum,
                                              const float* __restrict__ l1W,
                                              const float* __restrict__ l1b,
                                              const float* __restrict__ l2W,
                                              const float* __restrict__ l2b,
                                              const float* __restrict__ l3W,
                                              const float* __restrict__ l3b,
                                              float* __restrict__ out) {
    __shared__ float g[1024];
    __shared__ float part[1024];
    __shared__ float a1[128];
    __shared__ float a2[64];
    __shared__ float a3[10];
    const int tid = threadIdx.x;
    if (tid < 512) {
        g[tid]       = pool_max[tid] + pool_max[512 + tid] + pool_max[1024 + tid];
        g[512 + tid] = (pool_sum[tid] + pool_sum[512 + tid] + pool_sum[1024 + tid]) *
                       (1.0f / N_NODES);
    }
    __syncthreads();
    {
        int ch = tid & 127, sl = tid >> 7;
        float acc = (sl == 0) ? l1b[ch] : 0.f;
        int k0 = sl * 128;
        #pragma unroll 4
        for (int k = k0; k < k0 + 128; ++k) acc += g[k] * l1W[k * 128 + ch];
        part[tid] = acc;
    }
    __syncthreads();
    if (tid < 128) {
        float a = part[tid];
        #pragma unroll
        for (int ss = 1; ss < 8; ++ss) a += part[tid + ss * 128];
        a1[tid] = fmaxf(a, 0.f);
    }
    __syncthreads();
    if (tid < 512) {
        int ch = tid & 63, sl = tid >> 6;
        float acc = (sl == 0) ? l2b[ch] : 0.f;
        int k0 = sl * 16;
        #pragma unroll
        for (int k = k0; k < k0 + 16; ++k) acc += a1[k] * l2W[k * 64 + ch];
        part[tid] = acc;
    }
    __syncthreads();
    if (tid < 64) {
        float a = part[tid];
        #pragma unroll
        for (int ss = 1; ss < 8; ++ss) a += part[tid + ss * 64];
        a2[tid] = fmaxf(a, 0.f);
    }
    __syncthreads();
    if (tid < 10) {
        float acc = l3b[tid];
        for (int k = 0; k < 64; ++k) acc += a2[k] * l3W[k * 10 + tid];
        a3[tid] = acc;
    }
    __syncthreads();
    if (tid == 0) {
        float m = a3[0];
        for (int j = 1; j < 10; ++j) m = fmaxf(m, a3[j]);
        float ssum = 0.f;
        for (int j = 0; j < 10; ++j) ssum += expf(a3[j] - m);
        float lse = m + logf(ssum);
        for (int j = 0; j < 10; ++j) out[j] = a3[j] - lse;
    }
}

extern "C" void kernel_launch(void* const* d_in, const int* in_sizes, int n_in,
                              void* d_out, int out_size, void* d_ws, size_t ws_size,
                              hipStream_t stream) {
    const float* x    = (const float*)d_in[0];
    const int*   rows = (const int*)  d_in[1];
    const int*   cols = (const int*)  d_in[2];
    const float* vals = (const float*)d_in[3];
    const float* W1   = (const float*)d_in[4];
    const float* b1   = (const float*)d_in[5];
    const float* W2   = (const float*)d_in[6];
    const float* b2   = (const float*)d_in[7];
    const float* W3   = (const float*)d_in[8];
    const float* b3   = (const float*)d_in[9];
    const float* l1W  = (const float*)d_in[10];
    const float* l1b  = (const float*)d_in[11];
    const float* l2W  = (const float*)d_in[12];
    const float* l2b  = (const float*)d_in[13];
    const float* l3W  = (const float*)d_in[14];
    const float* l3b  = (const float*)d_in[15];
    float* out = (float*)d_out;

    char* ws = (char*)d_ws;
    size_t off = 0;
    auto alloc = [&](size_t bytes) {
        void* p = ws + off;
        off += (bytes + 255) & ~(size_t)255;
        return p;
    };
    ushort* xb       = (ushort*)alloc((size_t)N_NODES * HD * 2);
    ushort* s        = (ushort*)alloc((size_t)N_NODES * HD * 2);
    ushort* hb       = (ushort*)alloc((size_t)N_NODES * HD * 2);
    ushort* wt1      = (ushort*)alloc((size_t)HD * HD * 2);
    ushort* wt2      = (ushort*)alloc((size_t)HD * HD * 2);
    ushort* wt3      = (ushort*)alloc((size_t)HD * HD * 2);
    int*    deg      = (int*)   alloc((size_t)N_NODES * 4);
    float*  pmax     = (float*) alloc((size_t)3 * 512 * 4);
    float*  psum     = (float*) alloc((size_t)3 * 512 * 4);
    int*    rowstart = (int*)   alloc((size_t)(N_NODES + 1) * 4);
    int*    cursor   = (int*)   alloc((size_t)N_NODES * 4);
    int2*   csr_cv   = (int2*)  alloc((size_t)N_EDGES * 8);
    (void)ws_size; (void)in_sizes; (void)n_in; (void)out_size;

    // 1: prep (cvt + wt + zero deg/pmax/psum)
    prep_k<<<NB_CVT + NB_WT + NB_ZD + 12, 256, 0, stream>>>(
        x, xb, W1, W2, W3, wt1, wt2, wt3, deg, pmax, psum);
    // 2: gemm1 || hist
    fused1_k<<<628 + 1250, 256, 0, stream>>>(xb, wt1, s, rows, deg);
    // 3: scan
    scan_k<<<1, 1024, 0, stream>>>(deg, rowstart, cursor);
    // 4: fill CSR
    fill_k<<<(N_EDGES + 255) / 256, 256, 0, stream>>>(rows, cols, vals, cursor,
                                                      csr_cv);
    // 5: agg1
    agg_k<<<AGG_BLOCKS, 256, 0, stream>>>(s, rowstart, csr_cv, b1, hb);
    // 6: gemm2 || pool1
    fusedgp_k<<<628 + 256, 256, 0, stream>>>(hb, wt2, s, pmax, psum);
    // 7: agg2
    agg_k<<<AGG_BLOCKS, 256, 0, stream>>>(s, rowstart, csr_cv, b2, hb);
    // 8: gemm3 || pool2
    fusedgp_k<<<628 + 256, 256, 0, stream>>>(hb, wt3, s, pmax + 512, psum + 512);
    // 9: agg3
    agg_k<<<AGG_BLOCKS, 256, 0, stream>>>(s, rowstart, csr_cv, b3, hb);
    // 10: pool3
    pool_k<<<256, 256, 0, stream>>>(hb, pmax + 1024, psum + 1024);
    // 11: mlp head
    mlp_k<<<1, 1024, 0, stream>>>(pmax, psum, l1W, l1b, l2W, l2b, l3W, l3b, out);
}

// Round 5
// 379.524 us; speedup vs baseline: 1.4247x; 1.0972x over previous
//
#include <hip/hip_runtime.h>
#include <hip/hip_bf16.h>

#define N_NODES 20000
#define N_EDGES 320000
#define HD 512

typedef __attribute__((ext_vector_type(8))) short bf16x8;
typedef __attribute__((ext_vector_type(4))) float f32x4;

// ---------- bf16 helpers ----------
__device__ inline ushort f2bf(float f) {
    uint u = __float_as_uint(f);
    uint r = (u + 0x7fffu + ((u >> 16) & 1u)) >> 16;
    return (ushort)r;
}
__device__ inline uint pack2(float a, float b) {
    return (uint)f2bf(a) | ((uint)f2bf(b) << 16);
}
__device__ inline float bflo(uint u) { return __uint_as_float(u << 16); }
__device__ inline float bfhi(uint u) { return __uint_as_float(u & 0xffff0000u); }

__device__ __forceinline__ void async_load16(const void* g, void* l) {
    __builtin_amdgcn_global_load_lds(
        (const __attribute__((address_space(1))) uint*)g,
        (__attribute__((address_space(3))) uint*)l,
        16, 0, 0);
}

// ---------- gemm tile: 128x128, global_load_lds, XOR swizzle (proven) -------
__device__ __forceinline__ void gemm_tile(const ushort* __restrict__ A,
                                          const ushort* __restrict__ Bt,
                                          ushort* __restrict__ C,
                                          int tile, char* smem) {
    short* As = (short*)smem;
    short* Bs = (short*)(smem + 128 * 32 * 2);
    const int tid = threadIdx.x;
    const int lane = tid & 63;
    const int wave = tid >> 6;
    const int l15 = lane & 15;
    const int q = lane >> 4;
    const int wrow = wave >> 1, wcol = wave & 1;
    const int row0 = (tile >> 2) * 128;
    const int col0 = (tile & 3) * 128;

    const int srow = lane >> 2;
    const int kc   = (lane & 3) ^ ((lane >> 3) & 3);
    const int sl   = (l15 >> 1) & 3;

    f32x4 acc[4][4] = {};

    for (int k0 = 0; k0 < HD; k0 += 32) {
        #pragma unroll
        for (int l = 0; l < 2; ++l) {
            const int rbase = wave * 32 + l * 16;
            const ushort* ga = &A [(size_t)(row0 + rbase + srow) * HD + k0 + kc * 8];
            const ushort* gb = &Bt[(size_t)(col0 + rbase + srow) * HD + k0 + kc * 8];
            async_load16(ga, &As[rbase * 32]);
            async_load16(gb, &Bs[rbase * 32]);
        }
        __syncthreads();
        bf16x8 aF[4], bF[4];
        #pragma unroll
        for (int i = 0; i < 4; ++i)
            aF[i] = *(bf16x8*)&As[(wrow * 64 + i * 16 + l15) * 32 + (q ^ sl) * 8];
        #pragma unroll
        for (int j = 0; j < 4; ++j)
            bF[j] = *(bf16x8*)&Bs[(wcol * 64 + j * 16 + l15) * 32 + (q ^ sl) * 8];
        #pragma unroll
        for (int i = 0; i < 4; ++i)
            #pragma unroll
            for (int j = 0; j < 4; ++j)
                acc[i][j] = __builtin_amdgcn_mfma_f32_16x16x32_bf16(aF[i], bF[j], acc[i][j], 0, 0, 0);
        __syncthreads();
    }
    #pragma unroll
    for (int i = 0; i < 4; ++i) {
        #pragma unroll
        for (int r = 0; r < 4; ++r) {
            int gr = row0 + wrow * 64 + i * 16 + q * 4 + r;
            if (gr < N_NODES) {
                #pragma unroll
                for (int j = 0; j < 4; ++j) {
                    int gc = col0 + wcol * 64 + j * 16 + l15;
                    C[(size_t)gr * HD + gc] = f2bf(acc[i][j][r]);
                }
            }
        }
    }
}

// ---------- pool partial (proven) ----------
__device__ __forceinline__ void pool_part(const ushort* __restrict__ h,
                                          float* __restrict__ pmax,
                                          float* __restrict__ psum,
                                          int pb, char* smem) {
    float* lmx = (float*)smem;           // 2048 floats
    float* lsm = lmx + 2048;             // 2048 floats
    const int tid = threadIdx.x;
    const int wave = tid >> 6, lane = tid & 63;
    const uint4* h4 = (const uint4*)h;
    float m[8] = {}, sm[8] = {};
    for (int r = pb * 4 + wave; r < N_NODES; r += 1024) {
        uint4 v = h4[(size_t)r * 64 + lane];
        m[0] = fmaxf(m[0], bflo(v.x)); sm[0] += bflo(v.x);
        m[1] = fmaxf(m[1], bfhi(v.x)); sm[1] += bfhi(v.x);
        m[2] = fmaxf(m[2], bflo(v.y)); sm[2] += bflo(v.y);
        m[3] = fmaxf(m[3], bfhi(v.y)); sm[3] += bfhi(v.y);
        m[4] = fmaxf(m[4], bflo(v.z)); sm[4] += bflo(v.z);
        m[5] = fmaxf(m[5], bfhi(v.z)); sm[5] += bfhi(v.z);
        m[6] = fmaxf(m[6], bflo(v.w)); sm[6] += bflo(v.w);
        m[7] = fmaxf(m[7], bfhi(v.w)); sm[7] += bfhi(v.w);
    }
    #pragma unroll
    for (int i = 0; i < 8; ++i) {
        lmx[wave * 512 + lane * 8 + i] = m[i];
        lsm[wave * 512 + lane * 8 + i] = sm[i];
    }
    __syncthreads();
    #pragma unroll
    for (int cc = 0; cc < 2; ++cc) {
        int ch = tid * 2 + cc;
        float mx = fmaxf(fmaxf(lmx[ch], lmx[512 + ch]),
                         fmaxf(lmx[1024 + ch], lmx[1536 + ch]));
        float sv = (lsm[ch] + lsm[512 + ch]) + (lsm[1024 + ch] + lsm[1536 + ch]);
        atomicMax((int*)&pmax[ch], __float_as_int(mx));   // values >= 0
        atomicAdd(&psum[ch], sv);
    }
}

// ---------- prep: cvt x | wt transpose | zero deg/pmax/psum ----------
#define NB_CVT 5000
#define NB_WT  192
#define NB_ZD  79
__global__ __launch_bounds__(256) void prep_k(const float* __restrict__ x,
                                              ushort* __restrict__ xb,
                                              const float* __restrict__ W1,
                                              const float* __restrict__ W2,
                                              const float* __restrict__ W3,
                                              ushort* __restrict__ T1,
                                              ushort* __restrict__ T2,
                                              ushort* __restrict__ T3,
                                              int* __restrict__ deg,
                                              float* __restrict__ pmax,
                                              float* __restrict__ psum) {
    __shared__ float t[64][65];
    const int b = blockIdx.x;
    const int tid = threadIdx.x;
    if (b < NB_CVT) {
        int c = b * 256 + tid;
        const float4* p = (const float4*)x + (size_t)c * 2;
        float4 a = p[0], q = p[1];
        uint4 o;
        o.x = pack2(a.x, a.y); o.y = pack2(a.z, a.w);
        o.z = pack2(q.x, q.y); o.w = pack2(q.z, q.w);
        ((uint4*)xb)[c] = o;
    } else if (b < NB_CVT + NB_WT) {
        int idx = b - NB_CVT;
        int layer = idx >> 6, rem = idx & 63;
        const float* W = (layer == 0) ? W1 : (layer == 1) ? W2 : W3;
        ushort* T      = (layer == 0) ? T1 : (layer == 1) ? T2 : T3;
        int kb = (rem >> 3) * 64, nb = (rem & 7) * 64;
        int c = tid & 63, r4 = tid >> 6;
        #pragma unroll
        for (int l = 0; l < 16; ++l) {
            int r = l * 4 + r4;
            t[r][c] = W[(size_t)(kb + r) * HD + nb + c];
        }
        __syncthreads();
        #pragma unroll
        for (int l = 0; l < 16; ++l) {
            int r = l * 4 + r4;
            T[(size_t)(nb + r) * HD + kb + c] = f2bf(t[c][r]);
        }
    } else if (b < NB_CVT + NB_WT + NB_ZD) {
        int i = (b - NB_CVT - NB_WT) * 256 + tid;
        if (i < N_NODES) deg[i] = 0;
    } else if (b < NB_CVT + NB_WT + NB_ZD + 6) {
        int i = (b - NB_CVT - NB_WT - NB_ZD) * 256 + tid;
        pmax[i] = 0.f;
    } else {
        int i = (b - NB_CVT - NB_WT - NB_ZD - 6) * 256 + tid;
        psum[i] = 0.f;
    }
}

// ---------- fused1: gemm layer1 (0..627) || hist (628..1877) ----------
__global__ __launch_bounds__(256) void fused1_k(const ushort* __restrict__ xb,
                                                const ushort* __restrict__ wt1,
                                                ushort* __restrict__ s,
                                                const int* __restrict__ rows,
                                                int* __restrict__ deg) {
    __shared__ __align__(16) char smem[16384];
    const int b = blockIdx.x;
    if (b < 628) {
        gemm_tile(xb, wt1, s, b, smem);
    } else {
        int e = (b - 628) * 256 + threadIdx.x;   // 1250*256 == N_EDGES exactly
        atomicAdd(&deg[rows[e]], 1);
    }
}

// ---------- scan: one workgroup, 16 waves, shuffle (proven ~4 µs) ----------
__global__ __launch_bounds__(1024) void scan_k(const int* __restrict__ deg,
                                               int* __restrict__ rowstart,
                                               int* __restrict__ cursor) {
    __shared__ int wsum[16];
    const int tid = threadIdx.x;
    const int lane = tid & 63, wv = tid >> 6;
    int carry = 0;
    for (int base = 0; base < N_NODES; base += 1024) {
        int i = base + tid;
        int v = (i < N_NODES) ? deg[i] : 0;
        int incl = v;
        #pragma unroll
        for (int off = 1; off < 64; off <<= 1) {
            int t = __shfl_up(incl, off, 64);
            if (lane >= off) incl += t;
        }
        if (lane == 63) wsum[wv] = incl;
        __syncthreads();
        int woff = 0, tot = 0;
        #pragma unroll
        for (int w = 0; w < 16; ++w) {
            int sv = wsum[w];
            if (w < wv) woff += sv;
            tot += sv;
        }
        if (i < N_NODES) {
            int ex = carry + woff + incl - v;
            rowstart[i] = ex;
            cursor[i]   = ex;
        }
        carry += tot;
        __syncthreads();
    }
    if (tid == 0) rowstart[N_NODES] = carry;
}

// ---------- fill CSR (col+val packed into int2 -> one 8B load in agg) ------
__global__ void fill_k(const int* __restrict__ rows, const int* __restrict__ cols,
                       const float* __restrict__ vals, int* __restrict__ cursor,
                       int2* __restrict__ csr_cv) {
    int e = blockIdx.x * blockDim.x + threadIdx.x;
    if (e < N_EDGES) {
        int p = atomicAdd(&cursor[rows[e]], 1);
        csr_cv[p] = make_int2(cols[e], __float_as_int(vals[e]));
    }
}

// ---------- aggregate v5: sliced + XCD-pinned + group-owns-row, pipelined ---
// r4 post-mortem: 53us with VALU 37%, L2 6.2/34.5 TB/s, fabric 0.5 TB/s ->
// latency-bound. Causes: (a) only 15.6 waves/CU (1000 blocks), (b) branchy
// for(;;){if/else} loop = serial meta->gather chain per trip, no cross-trip
// overlap. Fix: RPG=2 -> 2504 blocks (~32 waves/CU); straight-line row loop;
// inner loop 4 edges/trip with NEXT trip's metadata prefetched during this
// trip's gathers (clamped idx, masked weights, branchless). 32 gathers in
// flight per wave. Slicing/pinning/int2-meta unchanged (proven).
__device__ inline void fma8(float* acc, uint4 v, float w) {
    acc[0] += w * bflo(v.x); acc[1] += w * bfhi(v.x);
    acc[2] += w * bflo(v.y); acc[3] += w * bfhi(v.y);
    acc[4] += w * bflo(v.z); acc[5] += w * bfhi(v.z);
    acc[6] += w * bflo(v.w); acc[7] += w * bfhi(v.w);
}

#define RPG 2                                    // rows per 8-lane group
#define AGG_RPB (32 * RPG)                       // 64 rows per block
#define AGG_CHUNKS ((N_NODES + AGG_RPB - 1) / AGG_RPB)   // 313
#define AGG_BLOCKS (8 * AGG_CHUNKS)              // 2504

__global__ __launch_bounds__(256) void agg_k(const ushort* __restrict__ s,
                                             const int* __restrict__ rowstart,
                                             const int2* __restrict__ csr_cv,
                                             const float* __restrict__ bias,
                                             ushort* __restrict__ hout) {
    const int slice = blockIdx.x & 7;            // XCD-pinned channel slice
    const int cidx  = blockIdx.x >> 3;           // 0..312
    const int wave = threadIdx.x >> 6, lane = threadIdx.x & 63;
    const int g = lane >> 3, sub = lane & 7;     // group, 16B channel chunk
    const uint4* s4 = (const uint4*)s;
    const size_t sbase = (size_t)slice * 8 + sub;
    uint4* houtp = (uint4*)hout + slice * 8 + sub;
    const float4 b0 = ((const float4*)bias)[slice * 16 + sub * 2];
    const float4 b1 = ((const float4*)bias)[slice * 16 + sub * 2 + 1];
    const int rbase = cidx * AGG_RPB + wave * (8 * RPG) + g * RPG;

    #pragma unroll
    for (int rr = 0; rr < RPG; ++rr) {
        const int r = rbase + rr;
        int beg = rowstart[r];                   // ws-safe even for pad rows
        int end = rowstart[r + 1];
        if (r >= N_NODES) { beg = 0; end = 0; }  // padded tail rows: no work
        float acc[8] = {};
        int j = beg;
        int2 m0, m1, m2, m3;
        if (j < end) {                           // prime the meta pipeline
            m0 = csr_cv[j];
            m1 = csr_cv[(j + 1 < end) ? j + 1 : end - 1];
            m2 = csr_cv[(j + 2 < end) ? j + 2 : end - 1];
            m3 = csr_cv[(j + 3 < end) ? j + 3 : end - 1];
        }
        while (j < end) {
            const int jn = j + 4;
            const int cl = end - 1;
            // prefetch next trip's metadata (clamped; overlaps the gathers)
            int2 n0 = csr_cv[(jn     < end) ? jn     : cl];
            int2 n1 = csr_cv[(jn + 1 < end) ? jn + 1 : cl];
            int2 n2 = csr_cv[(jn + 2 < end) ? jn + 2 : cl];
            int2 n3 = csr_cv[(jn + 3 < end) ? jn + 3 : cl];
            // 4 independent 128B gathers in flight per group
            uint4 v0 = s4[(size_t)m0.x * 64 + sbase];
            uint4 v1 = s4[(size_t)m1.x * 64 + sbase];
            uint4 v2 = s4[(size_t)m2.x * 64 + sbase];
            uint4 v3 = s4[(size_t)m3.x * 64 + sbase];
            float w0 = __int_as_float(m0.y);     // j < end always valid
            float w1 = (j + 1 < end) ? __int_as_float(m1.y) : 0.f;
            float w2 = (j + 2 < end) ? __int_as_float(m2.y) : 0.f;
            float w3 = (j + 3 < end) ? __int_as_float(m3.y) : 0.f;
            fma8(acc, v0, w0);
            fma8(acc, v1, w1);
            fma8(acc, v2, w2);
            fma8(acc, v3, w3);
            m0 = n0; m1 = n1; m2 = n2; m3 = n3;
            j = jn;
        }
        if (r < N_NODES) {                       // flush row (8 lanes = 128B)
            uint4 ov;
            ov.x = pack2(fmaxf(acc[0] + b0.x, 0.f), fmaxf(acc[1] + b0.y, 0.f));
            ov.y = pack2(fmaxf(acc[2] + b0.z, 0.f), fmaxf(acc[3] + b0.w, 0.f));
            ov.z = pack2(fmaxf(acc[4] + b1.x, 0.f), fmaxf(acc[5] + b1.y, 0.f));
            ov.w = pack2(fmaxf(acc[6] + b1.z, 0.f), fmaxf(acc[7] + b1.w, 0.f));
            houtp[(size_t)r * 64] = ov;
        }
    }
}

// ---------- fused gemm || pool (both read-only on h; proven) ----------
__global__ __launch_bounds__(256) void fusedgp_k(const ushort* __restrict__ h,
                                                 const ushort* __restrict__ wt,
                                                 ushort* __restrict__ s,
                                                 float* __restrict__ pmax,
                                                 float* __restrict__ psum) {
    __shared__ __align__(16) char smem[16384];
    const int b = blockIdx.x;
    if (b < 628) gemm_tile(h, wt, s, b, smem);
    else         pool_part(h, pmax, psum, b - 628, smem);
}

// ---------- standalone pool (layer 3) ----------
__global__ __launch_bounds__(256) void pool_k(const ushort* __restrict__ h,
                                              float* __restrict__ pmax,
                                              float* __restrict__ psum) {
    __shared__ __align__(16) char smem[16384];
    pool_part(h, pmax, psum, blockIdx.x, smem);
}

// ---------- head MLP + log_softmax (1024 threads, split-k; proven) ----------
__global__ __launch_bounds__(1024) void mlp_k(const float* __restrict__ pool_max,
                                              const float* __restrict__ pool_sum,
                                              const float* __restrict__ l1W,
                                              const float* __restrict__ l1b,
                                              const float* __restrict__ l2W,
                                              const float* __restrict__ l2b,
                                              const float* __restrict__ l3W,
                                              const float* __restrict__ l3b,
                                              float* __restrict__ out) {
    __shared__ float g[1024];
    __shared__ float part[1024];
    __shared__ float a1[128];
    __shared__ float a2[64];
    __shared__ float a3[10];
    const int tid = threadIdx.x;
    if (tid < 512) {
        g[tid]       = pool_max[tid] + pool_max[512 + tid] + pool_max[1024 + tid];
        g[512 + tid] = (pool_sum[tid] + pool_sum[512 + tid] + pool_sum[1024 + tid]) *
                       (1.0f / N_NODES);
    }
    __syncthreads();
    {
        int ch = tid & 127, sl = tid >> 7;
        float acc = (sl == 0) ? l1b[ch] : 0.f;
        int k0 = sl * 128;
        #pragma unroll 4
        for (int k = k0; k < k0 + 128; ++k) acc += g[k] * l1W[k * 128 + ch];
        part[tid] = acc;
    }
    __syncthreads();
    if (tid < 128) {
        float a = part[tid];
        #pragma unroll
        for (int ss = 1; ss < 8; ++ss) a += part[tid + ss * 128];
        a1[tid] = fmaxf(a, 0.f);
    }
    __syncthreads();
    if (tid < 512) {
        int ch = tid & 63, sl = tid >> 6;
        float acc = (sl == 0) ? l2b[ch] : 0.f;
        int k0 = sl * 16;
        #pragma unroll
        for (int k = k0; k < k0 + 16; ++k) acc += a1[k] * l2W[k * 64 + ch];
        part[tid] = acc;
    }
    __syncthreads();
    if (tid < 64) {
        float a = part[tid];
        #pragma unroll
        for (int ss = 1; ss < 8; ++ss) a += part[tid + ss * 64];
        a2[tid] = fmaxf(a, 0.f);
    }
    __syncthreads();
    if (tid < 10) {
        float acc = l3b[tid];
        for (int k = 0; k < 64; ++k) acc += a2[k] * l3W[k * 10 + tid];
        a3[tid] = acc;
    }
    __syncthreads();
    if (tid == 0) {
        float m = a3[0];
        for (int j = 1; j < 10; ++j) m = fmaxf(m, a3[j]);
        float ssum = 0.f;
        for (int j = 0; j < 10; ++j) ssum += expf(a3[j] - m);
        float lse = m + logf(ssum);
        for (int j = 0; j < 10; ++j) out[j] = a3[j] - lse;
    }
}

extern "C" void kernel_launch(void* const* d_in, const int* in_sizes, int n_in,
                              void* d_out, int out_size, void* d_ws, size_t ws_size,
                              hipStream_t stream) {
    const float* x    = (const float*)d_in[0];
    const int*   rows = (const int*)  d_in[1];
    const int*   cols = (const int*)  d_in[2];
    const float* vals = (const float*)d_in[3];
    const float* W1   = (const float*)d_in[4];
    const float* b1   = (const float*)d_in[5];
    const float* W2   = (const float*)d_in[6];
    const float* b2   = (const float*)d_in[7];
    const float* W3   = (const float*)d_in[8];
    const float* b3   = (const float*)d_in[9];
    const float* l1W  = (const float*)d_in[10];
    const float* l1b  = (const float*)d_in[11];
    const float* l2W  = (const float*)d_in[12];
    const float* l2b  = (const float*)d_in[13];
    const float* l3W  = (const float*)d_in[14];
    const float* l3b  = (const float*)d_in[15];
    float* out = (float*)d_out;

    char* ws = (char*)d_ws;
    size_t off = 0;
    auto alloc = [&](size_t bytes) {
        void* p = ws + off;
        off += (bytes + 255) & ~(size_t)255;
        return p;
    };
    ushort* xb       = (ushort*)alloc((size_t)N_NODES * HD * 2);
    ushort* s        = (ushort*)alloc((size_t)N_NODES * HD * 2);
    ushort* hb       = (ushort*)alloc((size_t)N_NODES * HD * 2);
    ushort* wt1      = (ushort*)alloc((size_t)HD * HD * 2);
    ushort* wt2      = (ushort*)alloc((size_t)HD * HD * 2);
    ushort* wt3      = (ushort*)alloc((size_t)HD * HD * 2);
    int*    deg      = (int*)   alloc((size_t)N_NODES * 4);
    float*  pmax     = (float*) alloc((size_t)3 * 512 * 4);
    float*  psum     = (float*) alloc((size_t)3 * 512 * 4);
    int*    rowstart = (int*)   alloc((size_t)(N_NODES + 1) * 4);
    int*    cursor   = (int*)   alloc((size_t)N_NODES * 4);
    int2*   csr_cv   = (int2*)  alloc((size_t)N_EDGES * 8);
    (void)ws_size; (void)in_sizes; (void)n_in; (void)out_size;

    // 1: prep (cvt + wt + zero deg/pmax/psum)
    prep_k<<<NB_CVT + NB_WT + NB_ZD + 12, 256, 0, stream>>>(
        x, xb, W1, W2, W3, wt1, wt2, wt3, deg, pmax, psum);
    // 2: gemm1 || hist
    fused1_k<<<628 + 1250, 256, 0, stream>>>(xb, wt1, s, rows, deg);
    // 3: scan
    scan_k<<<1, 1024, 0, stream>>>(deg, rowstart, cursor);
    // 4: fill CSR
    fill_k<<<(N_EDGES + 255) / 256, 256, 0, stream>>>(rows, cols, vals, cursor,
                                                      csr_cv);
    // 5: agg1
    agg_k<<<AGG_BLOCKS, 256, 0, stream>>>(s, rowstart, csr_cv, b1, hb);
    // 6: gemm2 || pool1
    fusedgp_k<<<628 + 256, 256, 0, stream>>>(hb, wt2, s, pmax, psum);
    // 7: agg2
    agg_k<<<AGG_BLOCKS, 256, 0, stream>>>(s, rowstart, csr_cv, b2, hb);
    // 8: gemm3 || pool2
    fusedgp_k<<<628 + 256, 256, 0, stream>>>(hb, wt3, s, pmax + 512, psum + 512);
    // 9: agg3
    agg_k<<<AGG_BLOCKS, 256, 0, stream>>>(s, rowstart, csr_cv, b3, hb);
    // 10: pool3
    pool_k<<<256, 256, 0, stream>>>(hb, pmax + 1024, psum + 1024);
    // 11: mlp head
    mlp_k<<<1, 1024, 0, stream>>>(pmax, psum, l1W, l1b, l2W, l2b, l3W, l3b, out);
}